// Round 1
// baseline (2250.870 us; speedup 1.0000x reference)
//
#include <hip/hip_runtime.h>
#include <hip/hip_bf16.h>

#define DEVFN __device__ __forceinline__

DEVFN float siluf(float x)     { return x / (1.f + __expf(-x)); }
DEVFN float softplusf(float x) { return fmaxf(x, 0.f) + log1pf(__expf(-fabsf(x))); }

// ---------------------------------------------------------------------------
// Generic tiled fp32 GEMM.
//   C[b, m, n] (OUTM) or C[b, n, m] (!OUTM) = sum_k A[m,k] * Xb[n,k 'BKC'] or Xb[k,n]
// A is (M,K) k-contiguous. X per batch: BKC ? (N,K) k-contig : (K,N) n-contig.
template<bool BKC, bool OUTM, bool CLIP, bool BIAS>
__global__ __launch_bounds__(256) void gemm_kernel(
    const float* __restrict__ A, const float* __restrict__ X,
    const float* __restrict__ bias, float* __restrict__ C,
    int M, int N, int K, long long Xbs, long long Cbs)
{
    __shared__ __align__(16) float As[16][68];
    __shared__ __align__(16) float Xs[16][68];
    const int m0 = blockIdx.x * 64;
    const int n0 = blockIdx.y * 64;
    const int b  = blockIdx.z;
    const float* Xb = X + (long long)b * Xbs;
    const int tid = threadIdx.x;
    const int te = tid & 15, tl = tid >> 4;
    float acc[4][4] = {};

    for (int k0 = 0; k0 < K; k0 += 16) {
        #pragma unroll
        for (int idx = tid; idx < 1024; idx += 256) {
            int e = idx >> 4, kk = idx & 15;
            int m = m0 + e, k = k0 + kk;
            As[kk][e] = (m < M && k < K) ? A[(long long)m * K + k] : 0.f;
        }
        if (BKC) {
            #pragma unroll
            for (int idx = tid; idx < 1024; idx += 256) {
                int n = idx >> 4, kk = idx & 15;
                int nn = n0 + n, k = k0 + kk;
                Xs[kk][n] = (nn < N && k < K) ? Xb[(long long)nn * K + k] : 0.f;
            }
        } else {
            #pragma unroll
            for (int idx = tid; idx < 1024; idx += 256) {
                int kk = idx >> 6, n = idx & 63;
                int nn = n0 + n, k = k0 + kk;
                Xs[kk][n] = (nn < N && k < K) ? Xb[(long long)k * N + nn] : 0.f;
            }
        }
        __syncthreads();
        #pragma unroll
        for (int kk = 0; kk < 16; ++kk) {
            float4 a4 = *reinterpret_cast<const float4*>(&As[kk][te * 4]);
            float4 x4 = *reinterpret_cast<const float4*>(&Xs[kk][tl * 4]);
            float av[4] = {a4.x, a4.y, a4.z, a4.w};
            float xv[4] = {x4.x, x4.y, x4.z, x4.w};
            #pragma unroll
            for (int i = 0; i < 4; ++i)
                #pragma unroll
                for (int j = 0; j < 4; ++j)
                    acc[i][j] += av[i] * xv[j];
        }
        __syncthreads();
    }

    #pragma unroll
    for (int i = 0; i < 4; ++i) {
        int m = m0 + te * 4 + i;
        if (m >= M) continue;
        float bv = BIAS ? bias[m] : 0.f;
        #pragma unroll
        for (int j = 0; j < 4; ++j) {
            int n = n0 + tl * 4 + j;
            if (n >= N) continue;
            float v = acc[i][j] + bv;
            if (CLIP) v = fminf(fmaxf(v, -6.f), 6.f);
            if (OUTM) C[(long long)b * Cbs + (long long)m * N + n] = v;
            else      C[(long long)b * Cbs + (long long)n * M + m] = v;
        }
    }
}

// ---------------------------------------------------------------------------
// Causal depthwise conv (width W) + SiLU. Input: first D channels of an
// (B, IC, L) channels-major tensor. Output (B, D, L).
__global__ __launch_bounds__(256) void conv_silu_kernel(
    const float* __restrict__ in, const float* __restrict__ w,
    const float* __restrict__ bias, float* __restrict__ out,
    int B, int D, int L, int W, int IC)
{
    int idx = blockIdx.x * 256 + threadIdx.x;
    int total = B * D * L;
    if (idx >= total) return;
    int l = idx % L;
    int d = (idx / L) % D;
    int b = idx / (L * D);
    const float* xp = in + (size_t)b * IC * L + (size_t)d * L;
    float acc = bias[d];
    for (int i = 0; i < W; ++i) {
        int li = l - (W - 1) + i;
        if (li >= 0) acc += w[d * W + i] * xp[li];
    }
    out[(size_t)b * D * L + (size_t)d * L + l] = siluf(acc);
}

// ---------------------------------------------------------------------------
// Outer selective scan. 16 lanes per channel (one per state). Block = 256
// threads = 16 channels. grid = (Dch/16, B). y may alias delta (same-thread
// read-then-write of the same element).
__global__ __launch_bounds__(256) void scan_outer_kernel(
    const float* __restrict__ delta, const float* __restrict__ u,
    const float* __restrict__ xz, const float* __restrict__ xdbl,
    const float* __restrict__ A_log, const float* __restrict__ Dp,
    const float* __restrict__ dt_bias, float* __restrict__ y,
    int Dch, int L)
{
    const int tid = threadIdx.x;
    const int n = tid & 15;
    const int ci = tid >> 4;
    const int d = blockIdx.x * 16 + ci;
    const int b = blockIdx.y;

    const size_t base = (size_t)b * Dch * L + (size_t)d * L;
    const float* dl_p = delta + base;
    const float* u_p  = u + base;
    const float* z_p  = xz + ((size_t)b * 2 * Dch + Dch + d) * L;
    const float* b_p  = xdbl + ((size_t)b * 96 + 64 + n) * L;
    const float* c_p  = xdbl + ((size_t)b * 96 + 80 + n) * L;

    const float Adn  = -__expf(A_log[d * 16 + n]);
    const float bias = dt_bias[d];
    const float Dd   = Dp[d];
    float s = 0.f;

    for (int l = 0; l < L; ++l) {
        float xv = dl_p[l] + bias;
        float dt = softplusf(xv);
        float ut = u_p[l];
        float bn = b_p[l], cn = c_p[l];
        s = s * __expf(dt * Adn) + dt * ut * bn;
        float p = s * cn;
        p += __shfl_xor(p, 1, 16);
        p += __shfl_xor(p, 2, 16);
        p += __shfl_xor(p, 4, 16);
        p += __shfl_xor(p, 8, 16);
        if (n == 0) {
            float zt = z_p[l];
            y[base + l] = (p + Dd * ut) * siluf(zt);
        }
    }
}

// ---------------------------------------------------------------------------
// Inner selective scan: 64 channels x 4 states per block, grid = B.
__global__ __launch_bounds__(256) void scan_inner_kernel(
    const float* __restrict__ mdelta, const float* __restrict__ mu,
    const float* __restrict__ mxz, const float* __restrict__ mxdbl,
    const float* __restrict__ mA_log, const float* __restrict__ mDp,
    const float* __restrict__ mdt_b, float* __restrict__ ym, int L)
{
    const int tid = threadIdx.x;
    const int n = tid & 3;
    const int d = tid >> 2;
    const int b = blockIdx.x;

    const size_t base = ((size_t)b * 64 + d) * L;
    const float* dl_p = mdelta + base;
    const float* u_p  = mu + base;
    const float* z_p  = mxz + ((size_t)b * 128 + 64 + d) * L;
    const float* b_p  = mxdbl + ((size_t)b * 12 + 4 + n) * L;
    const float* c_p  = mxdbl + ((size_t)b * 12 + 8 + n) * L;

    const float Adn  = -__expf(mA_log[d * 4 + n]);
    const float bias = mdt_b[d];
    const float Dd   = mDp[d];
    float s = 0.f;

    for (int l = 0; l < L; ++l) {
        float xv = dl_p[l] + bias;
        float dt = softplusf(xv);
        float ut = u_p[l];
        float bn = b_p[l], cn = c_p[l];
        s = s * __expf(dt * Adn) + dt * ut * bn;
        float p = s * cn;
        p += __shfl_xor(p, 1, 4);
        p += __shfl_xor(p, 2, 4);
        if (n == 0) {
            float zt = z_p[l];
            ym[base + l] = (p + Dd * ut) * siluf(zt);
        }
    }
}

// ---------------------------------------------------------------------------
extern "C" void kernel_launch(void* const* d_in, const int* in_sizes, int n_in,
                              void* d_out, int out_size, void* d_ws, size_t ws_size,
                              hipStream_t stream)
{
    const float* h         = (const float*)d_in[0];
    const float* in_w      = (const float*)d_in[1];
    const float* conv_w    = (const float*)d_in[2];
    const float* conv_b    = (const float*)d_in[3];
    const float* xproj_w   = (const float*)d_in[4];
    const float* dt_out_w  = (const float*)d_in[5];
    const float* dt_out_b  = (const float*)d_in[6];
    const float* A_log     = (const float*)d_in[7];
    const float* Dp        = (const float*)d_in[8];
    const float* out_w     = (const float*)d_in[9];
    const float* m_in_w    = (const float*)d_in[10];
    const float* m_conv_w  = (const float*)d_in[11];
    const float* m_conv_b  = (const float*)d_in[12];
    const float* m_xproj_w = (const float*)d_in[13];
    const float* m_dt_w    = (const float*)d_in[14];
    const float* m_dt_b    = (const float*)d_in[15];
    const float* m_A_log   = (const float*)d_in[16];
    const float* m_Dp      = (const float*)d_in[17];
    const float* m_out_w   = (const float*)d_in[18];
    float* out = (float*)d_out;

    const int B = 2, L = 1024, dm = 1024, di = 2048;

    float* ws     = (float*)d_ws;
    float* xz     = ws;                              // B*4096*L
    float* xconv  = xz     + (size_t)B * 2 * di * L; // B*2048*L
    float* xdbl   = xconv  + (size_t)B * di * L;     // B*96*L
    float* mxz    = xdbl   + (size_t)B * 96 * L;     // B*128*L
    float* mxconv = mxz    + (size_t)B * 128 * L;    // B*64*L
    float* mxdbl  = mxconv + (size_t)B * 64 * L;     // B*12*L
    float* mdelta = mxdbl  + (size_t)B * 12 * L;     // B*64*L
    float* ym     = mdelta + (size_t)B * 64 * L;     // B*64*L
    float* dtm    = ym     + (size_t)B * 64 * L;     // B*64*L
    float* delta  = dtm    + (size_t)B * 64 * L;     // B*2048*L (y aliases this)

    dim3 blk(256);

    // 1. xz[b,e,l] = sum_d h[b,l,d]*in_w[e,d]         (NT, out (b,e,l))
    gemm_kernel<true, true, false, false><<<dim3(64, 16, B), blk, 0, stream>>>(
        in_w, h, nullptr, xz, 2 * di, L, dm, (long long)L * dm, (long long)2 * di * L);

    // 2. x = silu(causal_conv(xz[:, :di]))
    {
        int total = B * di * L;
        conv_silu_kernel<<<dim3((total + 255) / 256), blk, 0, stream>>>(
            xz, conv_w, conv_b, xconv, B, di, L, 4, 2 * di);
    }

    // 3. xdbl[b,e,l] = sum_d xproj_w[e,d]*xconv[b,d,l]   (e<96)
    gemm_kernel<false, true, false, false><<<dim3(2, 16, B), blk, 0, stream>>>(
        xproj_w, xconv, nullptr, xdbl, 96, L, di, (long long)di * L, (long long)96 * L);

    // 4. inner mamba in_proj: mxz[b,e,l] = sum_d m_in_w[e,d]*xdbl[b,d,l] (d<64)
    gemm_kernel<false, true, false, false><<<dim3(2, 16, B), blk, 0, stream>>>(
        m_in_w, xdbl, nullptr, mxz, 128, L, 64, (long long)96 * L, (long long)128 * L);

    // 5. inner conv+silu (width 2)
    {
        int total = B * 64 * L;
        conv_silu_kernel<<<dim3((total + 255) / 256), blk, 0, stream>>>(
            mxz, m_conv_w, m_conv_b, mxconv, B, 64, L, 2, 128);
    }

    // 6. inner x_proj: mxdbl (12 rows)
    gemm_kernel<false, true, false, false><<<dim3(1, 16, B), blk, 0, stream>>>(
        m_xproj_w, mxconv, nullptr, mxdbl, 12, L, 64, (long long)64 * L, (long long)12 * L);

    // 7. inner delta: mdelta[b,d,l] = sum_r m_dt_w[d,r]*mxdbl[b,r,l] (r<4)
    gemm_kernel<false, true, false, false><<<dim3(1, 16, B), blk, 0, stream>>>(
        m_dt_w, mxdbl, nullptr, mdelta, 64, L, 4, (long long)12 * L, (long long)64 * L);

    // 8. inner selective scan -> ym
    scan_inner_kernel<<<dim3(B), blk, 0, stream>>>(
        mdelta, mxconv, mxz, mxdbl, m_A_log, m_Dp, m_dt_b, ym, L);

    // 9. inner out_proj: dtm[b,e,l] = sum_d m_out_w[e,d]*ym[b,d,l]
    gemm_kernel<false, true, false, false><<<dim3(1, 16, B), blk, 0, stream>>>(
        m_out_w, ym, nullptr, dtm, 64, L, 64, (long long)64 * L, (long long)64 * L);

    // 10. delta[b,d,l] = clip(sum_r dt_out_w[d,r]*dtm[b,r,l] + dt_out_b[d], +-6)
    gemm_kernel<false, true, true, true><<<dim3(32, 16, B), blk, 0, stream>>>(
        dt_out_w, dtm, dt_out_b, delta, di, L, 64, (long long)64 * L, (long long)di * L);

    // 11. outer selective scan -> y (aliases delta buffer)
    scan_outer_kernel<<<dim3(di / 16, B), blk, 0, stream>>>(
        delta, xconv, xz, xdbl, A_log, Dp, dt_out_b, delta, di, L);

    // 12. out[b,l,e] = sum_d out_w[e,d]*y[b,d,l]       (out (b,n,m))
    gemm_kernel<false, false, false, false><<<dim3(16, 16, B), blk, 0, stream>>>(
        out_w, delta, nullptr, out, dm, L, di, (long long)di * L, (long long)L * dm);
}

// Round 3
// 1207.206 us; speedup vs baseline: 1.8645x; 1.8645x over previous
//
#include <hip/hip_runtime.h>
#include <hip/hip_bf16.h>

#define DEVFN __device__ __forceinline__

DEVFN float siluf(float x)     { return x / (1.f + __expf(-x)); }
DEVFN float softplusf(float x) { return fmaxf(x, 0.f) + log1pf(__expf(-fabsf(x))); }

// ---------------------------------------------------------------------------
// Generic tiled fp32 GEMM.
//   C[b, m, n] (OUTM) or C[b, n, m] (!OUTM) = sum_k A[m,k] * Xb[n,k 'BKC'] or Xb[k,n]
// A is (M,K) k-contiguous. X per batch: BKC ? (N,K) k-contig : (K,N) n-contig.
template<bool BKC, bool OUTM, bool CLIP, bool BIAS>
__global__ __launch_bounds__(256) void gemm_kernel(
    const float* __restrict__ A, const float* __restrict__ X,
    const float* __restrict__ bias, float* __restrict__ C,
    int M, int N, int K, long long Xbs, long long Cbs)
{
    __shared__ __align__(16) float As[16][68];
    __shared__ __align__(16) float Xs[16][68];
    const int m0 = blockIdx.x * 64;
    const int n0 = blockIdx.y * 64;
    const int b  = blockIdx.z;
    const float* Xb = X + (long long)b * Xbs;
    const int tid = threadIdx.x;
    const int te = tid & 15, tl = tid >> 4;
    float acc[4][4] = {};

    for (int k0 = 0; k0 < K; k0 += 16) {
        #pragma unroll
        for (int idx = tid; idx < 1024; idx += 256) {
            int e = idx >> 4, kk = idx & 15;
            int m = m0 + e, k = k0 + kk;
            As[kk][e] = (m < M && k < K) ? A[(long long)m * K + k] : 0.f;
        }
        if (BKC) {
            #pragma unroll
            for (int idx = tid; idx < 1024; idx += 256) {
                int n = idx >> 4, kk = idx & 15;
                int nn = n0 + n, k = k0 + kk;
                Xs[kk][n] = (nn < N && k < K) ? Xb[(long long)nn * K + k] : 0.f;
            }
        } else {
            #pragma unroll
            for (int idx = tid; idx < 1024; idx += 256) {
                int kk = idx >> 6, n = idx & 63;
                int nn = n0 + n, k = k0 + kk;
                Xs[kk][n] = (nn < N && k < K) ? Xb[(long long)k * N + nn] : 0.f;
            }
        }
        __syncthreads();
        #pragma unroll
        for (int kk = 0; kk < 16; ++kk) {
            float4 a4 = *reinterpret_cast<const float4*>(&As[kk][te * 4]);
            float4 x4 = *reinterpret_cast<const float4*>(&Xs[kk][tl * 4]);
            float av[4] = {a4.x, a4.y, a4.z, a4.w};
            float xv[4] = {x4.x, x4.y, x4.z, x4.w};
            #pragma unroll
            for (int i = 0; i < 4; ++i)
                #pragma unroll
                for (int j = 0; j < 4; ++j)
                    acc[i][j] += av[i] * xv[j];
        }
        __syncthreads();
    }

    #pragma unroll
    for (int i = 0; i < 4; ++i) {
        int m = m0 + te * 4 + i;
        if (m >= M) continue;
        float bv = BIAS ? bias[m] : 0.f;
        #pragma unroll
        for (int j = 0; j < 4; ++j) {
            int n = n0 + tl * 4 + j;
            if (n >= N) continue;
            float v = acc[i][j] + bv;
            if (CLIP) v = fminf(fmaxf(v, -6.f), 6.f);
            if (OUTM) C[(long long)b * Cbs + (long long)m * N + n] = v;
            else      C[(long long)b * Cbs + (long long)n * M + m] = v;
        }
    }
}

// ---------------------------------------------------------------------------
// Causal depthwise conv (width W) + SiLU. Input: first D channels of an
// (B, IC, L) channels-major tensor. Output (B, D, L).
__global__ __launch_bounds__(256) void conv_silu_kernel(
    const float* __restrict__ in, const float* __restrict__ w,
    const float* __restrict__ bias, float* __restrict__ out,
    int B, int D, int L, int W, int IC)
{
    int idx = blockIdx.x * 256 + threadIdx.x;
    int total = B * D * L;
    if (idx >= total) return;
    int l = idx % L;
    int d = (idx / L) % D;
    int b = idx / (L * D);
    const float* xp = in + (size_t)b * IC * L + (size_t)d * L;
    float acc = bias[d];
    for (int i = 0; i < W; ++i) {
        int li = l - (W - 1) + i;
        if (li >= 0) acc += w[d * W + i] * xp[li];
    }
    out[(size_t)b * D * L + (size_t)d * L + l] = siluf(acc);
}

// ---------------------------------------------------------------------------
// Chunked-parallel outer selective scan.
// Block = 256 threads = 2 channels x (8 chunks x 16 states). Grid (Dch/2, B).
// Two-pass: chunk-local scan -> LDS combine of (decay, state) -> rescan+emit.
// y is a SEPARATE buffer (row stride L, batch stride Ybs) — no aliasing with
// any input of this kernel.
__global__ __launch_bounds__(256) void scan_outer2_kernel(
    const float* __restrict__ delta, const float* __restrict__ u,
    const float* __restrict__ xz, const float* __restrict__ xdbl,
    const float* __restrict__ A_log, const float* __restrict__ Dp,
    const float* __restrict__ dt_bias, float* __restrict__ y,
    int Dch, int L, long long Ybs)
{
    __shared__ float2 dtdu[2][1024];   // (dt, dt*u) per channel per l
    __shared__ float2 PS[2][16][8];    // (P, S) per channel, state, chunk

    const int tid = threadIdx.x;
    const int b  = blockIdx.y;
    const int d0 = blockIdx.x * 2;

    // phase 0: cooperative dt/du computation (8 l's per thread)
    {
        int ch = tid >> 7;
        int l0 = (tid & 127) * 8;
        int d  = d0 + ch;
        const float* dp = delta + ((size_t)b * Dch + d) * L + l0;
        const float* up = u     + ((size_t)b * Dch + d) * L + l0;
        float bias = dt_bias[d];
        float4 d4a = *(const float4*)(dp);
        float4 d4b = *(const float4*)(dp + 4);
        float4 u4a = *(const float4*)(up);
        float4 u4b = *(const float4*)(up + 4);
        float dv[8] = {d4a.x, d4a.y, d4a.z, d4a.w, d4b.x, d4b.y, d4b.z, d4b.w};
        float uv[8] = {u4a.x, u4a.y, u4a.z, u4a.w, u4b.x, u4b.y, u4b.z, u4b.w};
        #pragma unroll
        for (int t = 0; t < 8; ++t) {
            float dt = softplusf(dv[t] + bias);
            dtdu[ch][l0 + t] = make_float2(dt, dt * uv[t]);
        }
    }
    __syncthreads();

    const int ch = tid >> 7;
    const int t7 = tid & 127;
    const int c  = t7 >> 4;          // chunk 0..7 (128 steps each)
    const int n  = t7 & 15;          // state
    const int d  = d0 + ch;
    const float Adn = -__expf(A_log[d * 16 + n]);

    // phase 1: chunk-local scan (s_start = 0), accumulate sum(dt) for decay
    float s = 0.f, sumdt = 0.f;
    {
        const float* bp = xdbl + ((size_t)b * 96 + 64 + n) * L + c * 128;
        for (int q = 0; q < 32; ++q) {
            float4 b4 = *(const float4*)(bp + q * 4);
            float bv[4] = {b4.x, b4.y, b4.z, b4.w};
            #pragma unroll
            for (int t = 0; t < 4; ++t) {
                float2 dd = dtdu[ch][c * 128 + q * 4 + t];
                float a = __expf(dd.x * Adn);
                s = fmaf(a, s, dd.y * bv[t]);
                sumdt += dd.x;
            }
        }
    }
    PS[ch][n][c] = make_float2(__expf(sumdt * Adn), s);
    __syncthreads();

    // combine: chunk-initial state via serial fold over previous chunks
    float s0 = 0.f;
    for (int j = 0; j < c; ++j) {
        float2 ps = PS[ch][n][j];
        s0 = fmaf(ps.x, s0, ps.y);
    }

    // phase 2: rescan with correct init, reduce over states, emit y
    {
        const size_t ubase = ((size_t)b * Dch + d) * L + (size_t)c * 128;
        const size_t ybase = (size_t)b * Ybs + (size_t)d * L + (size_t)c * 128;
        const float* bp = xdbl + ((size_t)b * 96 + 64 + n) * L + c * 128;
        const float* cp = xdbl + ((size_t)b * 96 + 80 + n) * L + c * 128;
        const float* up = u + ubase;
        const float* zp = xz + ((size_t)b * 2 * Dch + Dch + d) * L + c * 128;
        const float Dd = Dp[d];
        float s2 = s0;
        for (int q = 0; q < 32; ++q) {
            float4 b4 = *(const float4*)(bp + q * 4);
            float4 c4 = *(const float4*)(cp + q * 4);
            float4 u4 = *(const float4*)(up + q * 4);
            float4 z4 = *(const float4*)(zp + q * 4);
            float bv[4] = {b4.x, b4.y, b4.z, b4.w};
            float cv[4] = {c4.x, c4.y, c4.z, c4.w};
            float uv[4] = {u4.x, u4.y, u4.z, u4.w};
            float zv[4] = {z4.x, z4.y, z4.z, z4.w};
            float yv[4];
            #pragma unroll
            for (int t = 0; t < 4; ++t) {
                float2 dd = dtdu[ch][c * 128 + q * 4 + t];
                float a = __expf(dd.x * Adn);
                s2 = fmaf(a, s2, dd.y * bv[t]);
                float p = s2 * cv[t];
                p += __shfl_xor(p, 1, 16);
                p += __shfl_xor(p, 2, 16);
                p += __shfl_xor(p, 4, 16);
                p += __shfl_xor(p, 8, 16);
                yv[t] = (p + Dd * uv[t]) * siluf(zv[t]);
            }
            if (n == 0)
                *(float4*)(y + ybase + q * 4) = make_float4(yv[0], yv[1], yv[2], yv[3]);
        }
    }
}

// ---------------------------------------------------------------------------
// Chunked-parallel inner selective scan. Block = one (b,d) channel:
// 256 threads = 64 chunks x 4 states, 16 steps per chunk. Grid (64, B).
__global__ __launch_bounds__(256) void scan_inner2_kernel(
    const float* __restrict__ mdelta, const float* __restrict__ mu,
    const float* __restrict__ mxz, const float* __restrict__ mxdbl,
    const float* __restrict__ mA_log, const float* __restrict__ mDp,
    const float* __restrict__ mdt_b, float* __restrict__ ym, int L)
{
    __shared__ float2 dtdu[1024];
    __shared__ float2 PS[4][64];

    const int tid = threadIdx.x;
    const int b = blockIdx.y;
    const int d = blockIdx.x;
    const size_t base = ((size_t)b * 64 + d) * L;

    // phase 0: dt/du for the whole row (4 l's per thread)
    {
        int l0 = tid * 4;
        float4 d4 = *(const float4*)(mdelta + base + l0);
        float4 u4 = *(const float4*)(mu + base + l0);
        float bias = mdt_b[d];
        float dv[4] = {d4.x, d4.y, d4.z, d4.w};
        float uv[4] = {u4.x, u4.y, u4.z, u4.w};
        #pragma unroll
        for (int t = 0; t < 4; ++t) {
            float dt = softplusf(dv[t] + bias);
            dtdu[l0 + t] = make_float2(dt, dt * uv[t]);
        }
    }
    __syncthreads();

    const int c = tid >> 2;      // chunk 0..63 (16 steps)
    const int n = tid & 3;       // state
    const float Adn = -__expf(mA_log[d * 4 + n]);

    // phase 1
    float s = 0.f, sumdt = 0.f;
    {
        const float* bp = mxdbl + ((size_t)b * 12 + 4 + n) * L + c * 16;
        for (int q = 0; q < 4; ++q) {
            float4 b4 = *(const float4*)(bp + q * 4);
            float bv[4] = {b4.x, b4.y, b4.z, b4.w};
            #pragma unroll
            for (int t = 0; t < 4; ++t) {
                float2 dd = dtdu[c * 16 + q * 4 + t];
                float a = __expf(dd.x * Adn);
                s = fmaf(a, s, dd.y * bv[t]);
                sumdt += dd.x;
            }
        }
    }
    PS[n][c] = make_float2(__expf(sumdt * Adn), s);
    __syncthreads();

    float s0 = 0.f;
    for (int j = 0; j < c; ++j) {
        float2 ps = PS[n][j];
        s0 = fmaf(ps.x, s0, ps.y);
    }

    // phase 2
    {
        const float* bp = mxdbl + ((size_t)b * 12 + 4 + n) * L + c * 16;
        const float* cp = mxdbl + ((size_t)b * 12 + 8 + n) * L + c * 16;
        const float* up = mu + base + c * 16;
        const float* zp = mxz + ((size_t)b * 128 + 64 + d) * L + c * 16;
        const float Dd = mDp[d];
        float s2 = s0;
        for (int q = 0; q < 4; ++q) {
            float4 b4 = *(const float4*)(bp + q * 4);
            float4 c4 = *(const float4*)(cp + q * 4);
            float4 u4 = *(const float4*)(up + q * 4);
            float4 z4 = *(const float4*)(zp + q * 4);
            float bv[4] = {b4.x, b4.y, b4.z, b4.w};
            float cv[4] = {c4.x, c4.y, c4.z, c4.w};
            float uv[4] = {u4.x, u4.y, u4.z, u4.w};
            float zv[4] = {z4.x, z4.y, z4.z, z4.w};
            float yv[4];
            #pragma unroll
            for (int t = 0; t < 4; ++t) {
                float2 dd = dtdu[c * 16 + q * 4 + t];
                float a = __expf(dd.x * Adn);
                s2 = fmaf(a, s2, dd.y * bv[t]);
                float p = s2 * cv[t];
                p += __shfl_xor(p, 1, 4);
                p += __shfl_xor(p, 2, 4);
                yv[t] = (p + Dd * uv[t]) * siluf(zv[t]);
            }
            if (n == 0)
                *(float4*)(ym + base + c * 16 + q * 4) = make_float4(yv[0], yv[1], yv[2], yv[3]);
        }
    }
}

// ---------------------------------------------------------------------------
extern "C" void kernel_launch(void* const* d_in, const int* in_sizes, int n_in,
                              void* d_out, int out_size, void* d_ws, size_t ws_size,
                              hipStream_t stream)
{
    const float* h         = (const float*)d_in[0];
    const float* in_w      = (const float*)d_in[1];
    const float* conv_w    = (const float*)d_in[2];
    const float* conv_b    = (const float*)d_in[3];
    const float* xproj_w   = (const float*)d_in[4];
    const float* dt_out_w  = (const float*)d_in[5];
    const float* dt_out_b  = (const float*)d_in[6];
    const float* A_log     = (const float*)d_in[7];
    const float* Dp        = (const float*)d_in[8];
    const float* out_w     = (const float*)d_in[9];
    const float* m_in_w    = (const float*)d_in[10];
    const float* m_conv_w  = (const float*)d_in[11];
    const float* m_conv_b  = (const float*)d_in[12];
    const float* m_xproj_w = (const float*)d_in[13];
    const float* m_dt_w    = (const float*)d_in[14];
    const float* m_dt_b    = (const float*)d_in[15];
    const float* m_A_log   = (const float*)d_in[16];
    const float* m_Dp      = (const float*)d_in[17];
    const float* m_out_w   = (const float*)d_in[18];
    float* out = (float*)d_out;

    const int B = 2, L = 1024, dm = 1024, di = 2048;

    float* ws     = (float*)d_ws;
    float* xz     = ws;                              // B*4096*L (x-rows reused as y)
    float* xconv  = xz     + (size_t)B * 2 * di * L; // B*2048*L
    float* xdbl   = xconv  + (size_t)B * di * L;     // B*96*L
    float* mxz    = xdbl   + (size_t)B * 96 * L;     // B*128*L
    float* mxconv = mxz    + (size_t)B * 128 * L;    // B*64*L
    float* mxdbl  = mxconv + (size_t)B * 64 * L;     // B*12*L
    float* mdelta = mxdbl  + (size_t)B * 12 * L;     // B*64*L
    float* ym     = mdelta + (size_t)B * 64 * L;     // B*64*L
    float* dtm    = ym     + (size_t)B * 64 * L;     // B*64*L
    float* delta  = dtm    + (size_t)B * 64 * L;     // B*2048*L

    dim3 blk(256);

    // 1. xz[b,e,l] = sum_d h[b,l,d]*in_w[e,d]         (NT, out (b,e,l))
    gemm_kernel<true, true, false, false><<<dim3(64, 16, B), blk, 0, stream>>>(
        in_w, h, nullptr, xz, 2 * di, L, dm, (long long)L * dm, (long long)2 * di * L);

    // 2. x = silu(causal_conv(xz[:, :di]))
    {
        int total = B * di * L;
        conv_silu_kernel<<<dim3((total + 255) / 256), blk, 0, stream>>>(
            xz, conv_w, conv_b, xconv, B, di, L, 4, 2 * di);
    }

    // 3. xdbl[b,e,l] = sum_d xproj_w[e,d]*xconv[b,d,l]   (e<96)
    gemm_kernel<false, true, false, false><<<dim3(2, 16, B), blk, 0, stream>>>(
        xproj_w, xconv, nullptr, xdbl, 96, L, di, (long long)di * L, (long long)96 * L);

    // 4. inner mamba in_proj: mxz[b,e,l] = sum_d m_in_w[e,d]*xdbl[b,d,l] (d<64)
    gemm_kernel<false, true, false, false><<<dim3(2, 16, B), blk, 0, stream>>>(
        m_in_w, xdbl, nullptr, mxz, 128, L, 64, (long long)96 * L, (long long)128 * L);

    // 5. inner conv+silu (width 2)
    {
        int total = B * 64 * L;
        conv_silu_kernel<<<dim3((total + 255) / 256), blk, 0, stream>>>(
            mxz, m_conv_w, m_conv_b, mxconv, B, 64, L, 2, 128);
    }

    // 6. inner x_proj: mxdbl (12 rows)
    gemm_kernel<false, true, false, false><<<dim3(1, 16, B), blk, 0, stream>>>(
        m_xproj_w, mxconv, nullptr, mxdbl, 12, L, 64, (long long)64 * L, (long long)12 * L);

    // 7. inner delta: mdelta[b,d,l] = sum_r m_dt_w[d,r]*mxdbl[b,r,l] (r<4)
    gemm_kernel<false, true, false, false><<<dim3(1, 16, B), blk, 0, stream>>>(
        m_dt_w, mxdbl, nullptr, mdelta, 64, L, 4, (long long)12 * L, (long long)64 * L);

    // 8. inner selective scan -> ym (chunk-parallel)
    scan_inner2_kernel<<<dim3(64, B), blk, 0, stream>>>(
        mdelta, mxconv, mxz, mxdbl, m_A_log, m_Dp, m_dt_b, ym, L);

    // 9. inner out_proj: dtm[b,e,l] = sum_d m_out_w[e,d]*ym[b,d,l]
    gemm_kernel<false, true, false, false><<<dim3(1, 16, B), blk, 0, stream>>>(
        m_out_w, ym, nullptr, dtm, 64, L, 64, (long long)64 * L, (long long)64 * L);

    // 10. delta[b,d,l] = clip(sum_r dt_out_w[d,r]*dtm[b,r,l] + dt_out_b[d], +-6)
    gemm_kernel<false, true, true, true><<<dim3(32, 16, B), blk, 0, stream>>>(
        dt_out_w, dtm, dt_out_b, delta, di, L, 64, (long long)64 * L, (long long)di * L);

    // 11. outer selective scan -> y, written into the (dead) x-rows of xz.
    //     No buffer is both read and written by this kernel.
    scan_outer2_kernel<<<dim3(di / 2, B), blk, 0, stream>>>(
        delta, xconv, xz, xdbl, A_log, Dp, dt_out_b, xz, di, L, (long long)2 * di * L);

    // 12. out[b,l,e] = sum_d out_w[e,d]*y[b,d,l]  (y = xz x-rows, batch stride 4096*L)
    gemm_kernel<false, false, false, false><<<dim3(16, 16, B), blk, 0, stream>>>(
        out_w, xz, nullptr, out, dm, L, di, (long long)2 * di * L, (long long)L * dm);
}

// Round 4
// 692.601 us; speedup vs baseline: 3.2499x; 1.7430x over previous
//
#include <hip/hip_runtime.h>
#include <hip/hip_bf16.h>

#define DEVFN __device__ __forceinline__

DEVFN float siluf(float x)     { return x / (1.f + __expf(-x)); }
DEVFN float softplusf(float x) { return fmaxf(x, 0.f) + log1pf(__expf(-fabsf(x))); }

DEVFN ushort f2bf(float f) {               // RNE fp32 -> bf16
    union { float f; unsigned u; } v; v.f = f;
    unsigned r = (v.u + 0x7FFF + ((v.u >> 16) & 1)) >> 16;
    return (ushort)r;
}

typedef __bf16 bf16x8 __attribute__((ext_vector_type(8)));
typedef float  f32x4  __attribute__((ext_vector_type(4)));
typedef ushort us8    __attribute__((ext_vector_type(8)));

// ---------------------------------------------------------------------------
// bf16 MFMA NT GEMM: C(M,N) += A(M,K) * B^T(N,K); A,B k-contiguous.
// A_F32/B_F32: source is fp32 (converted to bf16 during staging) else bf16.
// BM=128, BK=32, BN in {64,128}. 256 threads = 4 waves (2x2), per-wave
// 64 x BN/2 output via 4 x NFR 16x16x32 fragments. No bounds checks:
// M%128==0, N%BN==0, K%32==0 required.
template<int BN, bool A_F32, bool B_F32>
__global__ __launch_bounds__(256) void mfma_gemm_nt(
    const void* __restrict__ Av, const void* __restrict__ Bv,
    float* __restrict__ C, int M, int N, int K,
    long long Abs, long long Bbs, long long Cbs)
{
    constexpr int BM = 128;
    constexpr int NFR = BN / 32;           // N-fragments per wave
    __shared__ __align__(16) ushort As[BM][40];   // pad 8 bf16 = 16B
    __shared__ __align__(16) ushort Bs[BN][40];

    const int tid = threadIdx.x;
    const int m0 = blockIdx.x * BM;
    const int n0 = blockIdx.y * BN;
    const int b  = blockIdx.z;
    const int lane = tid & 63;
    const int wid  = tid >> 6;
    const int wr   = wid >> 1;             // wave row 0..1 (64 rows each)
    const int wc   = wid & 1;              // wave col 0..1 (BN/2 cols each)
    const int fr   = lane & 15;
    const int kq   = lane >> 4;            // k-quarter: k0 = kq*8

    f32x4 acc[4][NFR];
    #pragma unroll
    for (int i = 0; i < 4; ++i)
        #pragma unroll
        for (int j = 0; j < NFR; ++j)
            acc[i][j] = (f32x4){0.f, 0.f, 0.f, 0.f};

    const int arow = tid >> 1;             // staging: 2 threads per row
    const int kh   = (tid & 1) * 16;       // 16 elems each

    for (int kt = 0; kt < K; kt += 32) {
        if (kt) __syncthreads();
        // stage A tile (BM x 32)
        {
            const long long off = (long long)b * Abs + (long long)(m0 + arow) * K + kt + kh;
            us8 lo, hi;
            if (A_F32) {
                const float4* p = (const float4*)((const float*)Av + off);
                float4 v0 = p[0], v1 = p[1], v2 = p[2], v3 = p[3];
                lo = (us8){f2bf(v0.x), f2bf(v0.y), f2bf(v0.z), f2bf(v0.w),
                           f2bf(v1.x), f2bf(v1.y), f2bf(v1.z), f2bf(v1.w)};
                hi = (us8){f2bf(v2.x), f2bf(v2.y), f2bf(v2.z), f2bf(v2.w),
                           f2bf(v3.x), f2bf(v3.y), f2bf(v3.z), f2bf(v3.w)};
            } else {
                const us8* p = (const us8*)((const ushort*)Av + off);
                lo = p[0]; hi = p[1];
            }
            *(us8*)&As[arow][kh]     = lo;
            *(us8*)&As[arow][kh + 8] = hi;
        }
        // stage B tile (BN x 32)
        if (BN == BM || arow < BN) {
            const long long off = (long long)b * Bbs + (long long)(n0 + arow) * K + kt + kh;
            us8 lo, hi;
            if (B_F32) {
                const float4* p = (const float4*)((const float*)Bv + off);
                float4 v0 = p[0], v1 = p[1], v2 = p[2], v3 = p[3];
                lo = (us8){f2bf(v0.x), f2bf(v0.y), f2bf(v0.z), f2bf(v0.w),
                           f2bf(v1.x), f2bf(v1.y), f2bf(v1.z), f2bf(v1.w)};
                hi = (us8){f2bf(v2.x), f2bf(v2.y), f2bf(v2.z), f2bf(v2.w),
                           f2bf(v3.x), f2bf(v3.y), f2bf(v3.z), f2bf(v3.w)};
            } else {
                const us8* p = (const us8*)((const ushort*)Bv + off);
                lo = p[0]; hi = p[1];
            }
            *(us8*)&Bs[arow][kh]     = lo;
            *(us8*)&Bs[arow][kh + 8] = hi;
        }
        __syncthreads();

        bf16x8 af[4], bf[NFR];
        #pragma unroll
        for (int mi = 0; mi < 4; ++mi)
            af[mi] = *(const bf16x8*)&As[wr * 64 + mi * 16 + fr][kq * 8];
        #pragma unroll
        for (int ni = 0; ni < NFR; ++ni)
            bf[ni] = *(const bf16x8*)&Bs[wc * (BN / 2) + ni * 16 + fr][kq * 8];
        #pragma unroll
        for (int mi = 0; mi < 4; ++mi)
            #pragma unroll
            for (int ni = 0; ni < NFR; ++ni)
                acc[mi][ni] = __builtin_amdgcn_mfma_f32_16x16x32_bf16(
                    af[mi], bf[ni], acc[mi][ni], 0, 0, 0);
    }

    // epilogue: D col = lane&15, row = 4*(lane>>4)+reg
    #pragma unroll
    for (int mi = 0; mi < 4; ++mi) {
        const int gm = m0 + wr * 64 + mi * 16 + kq * 4;
        #pragma unroll
        for (int ni = 0; ni < NFR; ++ni) {
            const int gn = n0 + wc * (BN / 2) + ni * 16 + fr;
            f32x4 v = acc[mi][ni];
            #pragma unroll
            for (int r = 0; r < 4; ++r)
                C[(long long)b * Cbs + (long long)(gm + r) * N + gn] = v[r];
        }
    }
}

// ---------------------------------------------------------------------------
// y (b, D, L) fp32 (batch stride Ybs) -> yt (b, L, D) bf16 (contiguous).
__global__ __launch_bounds__(256) void transpose_f32_bf16(
    const float* __restrict__ y, ushort* __restrict__ yt,
    int D, int Lx, long long Ybs)
{
    __shared__ float ts[32][33];
    const int l0 = blockIdx.x * 32, d0 = blockIdx.y * 32, b = blockIdx.z;
    const int tx = threadIdx.x & 31, ty = threadIdx.x >> 5;
    const float* yb = y + (size_t)b * Ybs + (size_t)d0 * Lx + l0;
    #pragma unroll
    for (int r = ty; r < 32; r += 8)
        ts[r][tx] = yb[(size_t)r * Lx + tx];
    __syncthreads();
    ushort* ytb = yt + ((size_t)b * Lx + l0) * D + d0;
    #pragma unroll
    for (int r = ty; r < 32; r += 8)
        ytb[(size_t)r * D + tx] = f2bf(ts[tx][r]);
}

// ---------------------------------------------------------------------------
// Generic tiled fp32 GEMM (small ops).
template<bool BKC, bool OUTM, bool CLIP, bool BIAS>
__global__ __launch_bounds__(256) void gemm_kernel(
    const float* __restrict__ A, const float* __restrict__ X,
    const float* __restrict__ bias, float* __restrict__ C,
    int M, int N, int K, long long Xbs, long long Cbs)
{
    __shared__ __align__(16) float As[16][68];
    __shared__ __align__(16) float Xs[16][68];
    const int m0 = blockIdx.x * 64;
    const int n0 = blockIdx.y * 64;
    const int b  = blockIdx.z;
    const float* Xb = X + (long long)b * Xbs;
    const int tid = threadIdx.x;
    const int te = tid & 15, tl = tid >> 4;
    float acc[4][4] = {};

    for (int k0 = 0; k0 < K; k0 += 16) {
        #pragma unroll
        for (int idx = tid; idx < 1024; idx += 256) {
            int e = idx >> 4, kk = idx & 15;
            int m = m0 + e, k = k0 + kk;
            As[kk][e] = (m < M && k < K) ? A[(long long)m * K + k] : 0.f;
        }
        if (BKC) {
            #pragma unroll
            for (int idx = tid; idx < 1024; idx += 256) {
                int n = idx >> 4, kk = idx & 15;
                int nn = n0 + n, k = k0 + kk;
                Xs[kk][n] = (nn < N && k < K) ? Xb[(long long)nn * K + k] : 0.f;
            }
        } else {
            #pragma unroll
            for (int idx = tid; idx < 1024; idx += 256) {
                int kk = idx >> 6, n = idx & 63;
                int nn = n0 + n, k = k0 + kk;
                Xs[kk][n] = (nn < N && k < K) ? Xb[(long long)k * N + nn] : 0.f;
            }
        }
        __syncthreads();
        #pragma unroll
        for (int kk = 0; kk < 16; ++kk) {
            float4 a4 = *reinterpret_cast<const float4*>(&As[kk][te * 4]);
            float4 x4 = *reinterpret_cast<const float4*>(&Xs[kk][tl * 4]);
            float av[4] = {a4.x, a4.y, a4.z, a4.w};
            float xv[4] = {x4.x, x4.y, x4.z, x4.w};
            #pragma unroll
            for (int i = 0; i < 4; ++i)
                #pragma unroll
                for (int j = 0; j < 4; ++j)
                    acc[i][j] += av[i] * xv[j];
        }
        __syncthreads();
    }

    #pragma unroll
    for (int i = 0; i < 4; ++i) {
        int m = m0 + te * 4 + i;
        if (m >= M) continue;
        float bv = BIAS ? bias[m] : 0.f;
        #pragma unroll
        for (int j = 0; j < 4; ++j) {
            int n = n0 + tl * 4 + j;
            if (n >= N) continue;
            float v = acc[i][j] + bv;
            if (CLIP) v = fminf(fmaxf(v, -6.f), 6.f);
            if (OUTM) C[(long long)b * Cbs + (long long)m * N + n] = v;
            else      C[(long long)b * Cbs + (long long)n * M + m] = v;
        }
    }
}

// ---------------------------------------------------------------------------
__global__ __launch_bounds__(256) void conv_silu_kernel(
    const float* __restrict__ in, const float* __restrict__ w,
    const float* __restrict__ bias, float* __restrict__ out,
    int B, int D, int L, int W, int IC)
{
    int idx = blockIdx.x * 256 + threadIdx.x;
    int total = B * D * L;
    if (idx >= total) return;
    int l = idx % L;
    int d = (idx / L) % D;
    int b = idx / (L * D);
    const float* xp = in + (size_t)b * IC * L + (size_t)d * L;
    float acc = bias[d];
    for (int i = 0; i < W; ++i) {
        int li = l - (W - 1) + i;
        if (li >= 0) acc += w[d * W + i] * xp[li];
    }
    out[(size_t)b * D * L + (size_t)d * L + l] = siluf(acc);
}

// ---------------------------------------------------------------------------
// Chunked-parallel outer selective scan (2 ch x 8 chunks x 16 states / block).
__global__ __launch_bounds__(256) void scan_outer2_kernel(
    const float* __restrict__ delta, const float* __restrict__ u,
    const float* __restrict__ xz, const float* __restrict__ xdbl,
    const float* __restrict__ A_log, const float* __restrict__ Dp,
    const float* __restrict__ dt_bias, float* __restrict__ y,
    int Dch, int L, long long Ybs)
{
    __shared__ float2 dtdu[2][1024];
    __shared__ float2 PS[2][16][8];

    const int tid = threadIdx.x;
    const int b  = blockIdx.y;
    const int d0 = blockIdx.x * 2;

    {
        int ch = tid >> 7;
        int l0 = (tid & 127) * 8;
        int d  = d0 + ch;
        const float* dp = delta + ((size_t)b * Dch + d) * L + l0;
        const float* up = u     + ((size_t)b * Dch + d) * L + l0;
        float bias = dt_bias[d];
        float4 d4a = *(const float4*)(dp);
        float4 d4b = *(const float4*)(dp + 4);
        float4 u4a = *(const float4*)(up);
        float4 u4b = *(const float4*)(up + 4);
        float dv[8] = {d4a.x, d4a.y, d4a.z, d4a.w, d4b.x, d4b.y, d4b.z, d4b.w};
        float uv[8] = {u4a.x, u4a.y, u4a.z, u4a.w, u4b.x, u4b.y, u4b.z, u4b.w};
        #pragma unroll
        for (int t = 0; t < 8; ++t) {
            float dt = softplusf(dv[t] + bias);
            dtdu[ch][l0 + t] = make_float2(dt, dt * uv[t]);
        }
    }
    __syncthreads();

    const int ch = tid >> 7;
    const int t7 = tid & 127;
    const int c  = t7 >> 4;
    const int n  = t7 & 15;
    const int d  = d0 + ch;
    const float Adn = -__expf(A_log[d * 16 + n]);

    float s = 0.f, sumdt = 0.f;
    {
        const float* bp = xdbl + ((size_t)b * 96 + 64 + n) * L + c * 128;
        for (int q = 0; q < 32; ++q) {
            float4 b4 = *(const float4*)(bp + q * 4);
            float bv[4] = {b4.x, b4.y, b4.z, b4.w};
            #pragma unroll
            for (int t = 0; t < 4; ++t) {
                float2 dd = dtdu[ch][c * 128 + q * 4 + t];
                float a = __expf(dd.x * Adn);
                s = fmaf(a, s, dd.y * bv[t]);
                sumdt += dd.x;
            }
        }
    }
    PS[ch][n][c] = make_float2(__expf(sumdt * Adn), s);
    __syncthreads();

    float s0 = 0.f;
    for (int j = 0; j < c; ++j) {
        float2 ps = PS[ch][n][j];
        s0 = fmaf(ps.x, s0, ps.y);
    }

    {
        const size_t ubase = ((size_t)b * Dch + d) * L + (size_t)c * 128;
        const size_t ybase = (size_t)b * Ybs + (size_t)d * L + (size_t)c * 128;
        const float* bp = xdbl + ((size_t)b * 96 + 64 + n) * L + c * 128;
        const float* cp = xdbl + ((size_t)b * 96 + 80 + n) * L + c * 128;
        const float* up = u + ubase;
        const float* zp = xz + ((size_t)b * 2 * Dch + Dch + d) * L + c * 128;
        const float Dd = Dp[d];
        float s2 = s0;
        for (int q = 0; q < 32; ++q) {
            float4 b4 = *(const float4*)(bp + q * 4);
            float4 c4 = *(const float4*)(cp + q * 4);
            float4 u4 = *(const float4*)(up + q * 4);
            float4 z4 = *(const float4*)(zp + q * 4);
            float bv[4] = {b4.x, b4.y, b4.z, b4.w};
            float cv[4] = {c4.x, c4.y, c4.z, c4.w};
            float uv[4] = {u4.x, u4.y, u4.z, u4.w};
            float zv[4] = {z4.x, z4.y, z4.z, z4.w};
            float yv[4];
            #pragma unroll
            for (int t = 0; t < 4; ++t) {
                float2 dd = dtdu[ch][c * 128 + q * 4 + t];
                float a = __expf(dd.x * Adn);
                s2 = fmaf(a, s2, dd.y * bv[t]);
                float p = s2 * cv[t];
                p += __shfl_xor(p, 1, 16);
                p += __shfl_xor(p, 2, 16);
                p += __shfl_xor(p, 4, 16);
                p += __shfl_xor(p, 8, 16);
                yv[t] = (p + Dd * uv[t]) * siluf(zv[t]);
            }
            if (n == 0)
                *(float4*)(y + ybase + q * 4) = make_float4(yv[0], yv[1], yv[2], yv[3]);
        }
    }
}

// ---------------------------------------------------------------------------
// Chunked-parallel inner selective scan.
__global__ __launch_bounds__(256) void scan_inner2_kernel(
    const float* __restrict__ mdelta, const float* __restrict__ mu,
    const float* __restrict__ mxz, const float* __restrict__ mxdbl,
    const float* __restrict__ mA_log, const float* __restrict__ mDp,
    const float* __restrict__ mdt_b, float* __restrict__ ym, int L)
{
    __shared__ float2 dtdu[1024];
    __shared__ float2 PS[4][64];

    const int tid = threadIdx.x;
    const int b = blockIdx.y;
    const int d = blockIdx.x;
    const size_t base = ((size_t)b * 64 + d) * L;

    {
        int l0 = tid * 4;
        float4 d4 = *(const float4*)(mdelta + base + l0);
        float4 u4 = *(const float4*)(mu + base + l0);
        float bias = mdt_b[d];
        float dv[4] = {d4.x, d4.y, d4.z, d4.w};
        float uv[4] = {u4.x, u4.y, u4.z, u4.w};
        #pragma unroll
        for (int t = 0; t < 4; ++t) {
            float dt = softplusf(dv[t] + bias);
            dtdu[l0 + t] = make_float2(dt, dt * uv[t]);
        }
    }
    __syncthreads();

    const int c = tid >> 2;
    const int n = tid & 3;
    const float Adn = -__expf(mA_log[d * 4 + n]);

    float s = 0.f, sumdt = 0.f;
    {
        const float* bp = mxdbl + ((size_t)b * 12 + 4 + n) * L + c * 16;
        for (int q = 0; q < 4; ++q) {
            float4 b4 = *(const float4*)(bp + q * 4);
            float bv[4] = {b4.x, b4.y, b4.z, b4.w};
            #pragma unroll
            for (int t = 0; t < 4; ++t) {
                float2 dd = dtdu[c * 16 + q * 4 + t];
                float a = __expf(dd.x * Adn);
                s = fmaf(a, s, dd.y * bv[t]);
                sumdt += dd.x;
            }
        }
    }
    PS[n][c] = make_float2(__expf(sumdt * Adn), s);
    __syncthreads();

    float s0 = 0.f;
    for (int j = 0; j < c; ++j) {
        float2 ps = PS[n][j];
        s0 = fmaf(ps.x, s0, ps.y);
    }

    {
        const float* bp = mxdbl + ((size_t)b * 12 + 4 + n) * L + c * 16;
        const float* cp = mxdbl + ((size_t)b * 12 + 8 + n) * L + c * 16;
        const float* up = mu + base + c * 16;
        const float* zp = mxz + ((size_t)b * 128 + 64 + d) * L + c * 16;
        const float Dd = mDp[d];
        float s2 = s0;
        for (int q = 0; q < 4; ++q) {
            float4 b4 = *(const float4*)(bp + q * 4);
            float4 c4 = *(const float4*)(cp + q * 4);
            float4 u4 = *(const float4*)(up + q * 4);
            float4 z4 = *(const float4*)(zp + q * 4);
            float bv[4] = {b4.x, b4.y, b4.z, b4.w};
            float cv[4] = {c4.x, c4.y, c4.z, c4.w};
            float uv[4] = {u4.x, u4.y, u4.z, u4.w};
            float zv[4] = {z4.x, z4.y, z4.z, z4.w};
            float yv[4];
            #pragma unroll
            for (int t = 0; t < 4; ++t) {
                float2 dd = dtdu[c * 16 + q * 4 + t];
                float a = __expf(dd.x * Adn);
                s2 = fmaf(a, s2, dd.y * bv[t]);
                float p = s2 * cv[t];
                p += __shfl_xor(p, 1, 4);
                p += __shfl_xor(p, 2, 4);
                yv[t] = (p + Dd * uv[t]) * siluf(zv[t]);
            }
            if (n == 0)
                *(float4*)(ym + base + c * 16 + q * 4) = make_float4(yv[0], yv[1], yv[2], yv[3]);
        }
    }
}

// ---------------------------------------------------------------------------
extern "C" void kernel_launch(void* const* d_in, const int* in_sizes, int n_in,
                              void* d_out, int out_size, void* d_ws, size_t ws_size,
                              hipStream_t stream)
{
    const float* h         = (const float*)d_in[0];
    const float* in_w      = (const float*)d_in[1];
    const float* conv_w    = (const float*)d_in[2];
    const float* conv_b    = (const float*)d_in[3];
    const float* xproj_w   = (const float*)d_in[4];
    const float* dt_out_w  = (const float*)d_in[5];
    const float* dt_out_b  = (const float*)d_in[6];
    const float* A_log     = (const float*)d_in[7];
    const float* Dp        = (const float*)d_in[8];
    const float* out_w     = (const float*)d_in[9];
    const float* m_in_w    = (const float*)d_in[10];
    const float* m_conv_w  = (const float*)d_in[11];
    const float* m_conv_b  = (const float*)d_in[12];
    const float* m_xproj_w = (const float*)d_in[13];
    const float* m_dt_w    = (const float*)d_in[14];
    const float* m_dt_b    = (const float*)d_in[15];
    const float* m_A_log   = (const float*)d_in[16];
    const float* m_Dp      = (const float*)d_in[17];
    const float* m_out_w   = (const float*)d_in[18];
    float* out = (float*)d_out;

    const int B = 2, L = 1024, dm = 1024, di = 2048;

    float* ws     = (float*)d_ws;
    float* xz     = ws;                              // B*4096*L (x-rows reused as y)
    float* xconv  = xz     + (size_t)B * 2 * di * L; // B*2048*L
    float* xdbl   = xconv  + (size_t)B * di * L;     // B*96*L
    float* mxz    = xdbl   + (size_t)B * 96 * L;     // B*128*L
    float* mxconv = mxz    + (size_t)B * 128 * L;    // B*64*L
    float* mxdbl  = mxconv + (size_t)B * 64 * L;     // B*12*L
    float* mdelta = mxdbl  + (size_t)B * 12 * L;     // B*64*L
    float* ym     = mdelta + (size_t)B * 64 * L;     // B*64*L
    float* dtm    = ym     + (size_t)B * 64 * L;     // B*64*L
    float* delta  = dtm    + (size_t)B * 64 * L;     // B*2048*L
    ushort* yt    = (ushort*)delta;                  // bf16 y^T, reuses delta after scan

    dim3 blk(256);

    // 1. xz[b,e,l] = sum_d in_w[e,d]*h[b,l,d]   (bf16 MFMA NT, fp32 out)
    mfma_gemm_nt<128, true, true><<<dim3(4096 / 128, L / 128, B), blk, 0, stream>>>(
        in_w, h, xz, 2 * di, L, dm, 0LL, (long long)L * dm, (long long)2 * di * L);

    // 2. x = silu(causal_conv(xz[:, :di]))
    {
        int total = B * di * L;
        conv_silu_kernel<<<dim3((total + 255) / 256), blk, 0, stream>>>(
            xz, conv_w, conv_b, xconv, B, di, L, 4, 2 * di);
    }

    // 3. xdbl[b,e,l] = sum_d xproj_w[e,d]*xconv[b,d,l]   (e<96)
    gemm_kernel<false, true, false, false><<<dim3(2, 16, B), blk, 0, stream>>>(
        xproj_w, xconv, nullptr, xdbl, 96, L, di, (long long)di * L, (long long)96 * L);

    // 4. inner in_proj
    gemm_kernel<false, true, false, false><<<dim3(2, 16, B), blk, 0, stream>>>(
        m_in_w, xdbl, nullptr, mxz, 128, L, 64, (long long)96 * L, (long long)128 * L);

    // 5. inner conv+silu (width 2)
    {
        int total = B * 64 * L;
        conv_silu_kernel<<<dim3((total + 255) / 256), blk, 0, stream>>>(
            mxz, m_conv_w, m_conv_b, mxconv, B, 64, L, 2, 128);
    }

    // 6. inner x_proj
    gemm_kernel<false, true, false, false><<<dim3(1, 16, B), blk, 0, stream>>>(
        m_xproj_w, mxconv, nullptr, mxdbl, 12, L, 64, (long long)64 * L, (long long)12 * L);

    // 7. inner delta
    gemm_kernel<false, true, false, false><<<dim3(1, 16, B), blk, 0, stream>>>(
        m_dt_w, mxdbl, nullptr, mdelta, 64, L, 4, (long long)12 * L, (long long)64 * L);

    // 8. inner selective scan -> ym
    scan_inner2_kernel<<<dim3(64, B), blk, 0, stream>>>(
        mdelta, mxconv, mxz, mxdbl, m_A_log, m_Dp, m_dt_b, ym, L);

    // 9. inner out_proj
    gemm_kernel<false, true, false, false><<<dim3(1, 16, B), blk, 0, stream>>>(
        m_out_w, ym, nullptr, dtm, 64, L, 64, (long long)64 * L, (long long)64 * L);

    // 10. delta = clip(dt_out_w @ dtm + dt_out_b, +-6)
    gemm_kernel<false, true, true, true><<<dim3(32, 16, B), blk, 0, stream>>>(
        dt_out_w, dtm, dt_out_b, delta, di, L, 64, (long long)64 * L, (long long)di * L);

    // 11. outer selective scan -> y into the dead x-rows of xz (fp32)
    scan_outer2_kernel<<<dim3(di / 2, B), blk, 0, stream>>>(
        delta, xconv, xz, xdbl, A_log, Dp, dt_out_b, xz, di, L, (long long)2 * di * L);

    // 11b. y (b,di,L in xz rows) -> yt (b,L,di) bf16 (delta buffer is dead now)
    transpose_f32_bf16<<<dim3(L / 32, di / 32, B), blk, 0, stream>>>(
        xz, yt, di, L, (long long)2 * di * L);

    // 12. out[(b,l),e] = sum_d yt[(b,l),d]*out_w[e,d]  (batch-merged M=2048)
    mfma_gemm_nt<64, false, true><<<dim3(B * L / 128, dm / 64, 1), blk, 0, stream>>>(
        yt, out_w, out, B * L, dm, di, 0LL, 0LL, 0LL);
}

// Round 5
// 402.547 us; speedup vs baseline: 5.5916x; 1.7205x over previous
//
#include <hip/hip_runtime.h>
#include <hip/hip_bf16.h>

#define DEVFN __device__ __forceinline__

DEVFN float siluf(float x)     { return x / (1.f + __expf(-x)); }
DEVFN float softplusf(float x) { return fmaxf(x, 0.f) + log1pf(__expf(-fabsf(x))); }

DEVFN ushort f2bf(float f) {               // RNE fp32 -> bf16
    union { float f; unsigned u; } v; v.f = f;
    unsigned r = (v.u + 0x7FFF + ((v.u >> 16) & 1)) >> 16;
    return (ushort)r;
}

typedef __bf16 bf16x8 __attribute__((ext_vector_type(8)));
typedef float  f32x4  __attribute__((ext_vector_type(4)));
typedef ushort us8    __attribute__((ext_vector_type(8)));

// ---------------------------------------------------------------------------
// bf16 MFMA NT GEMM: C(M,N) += A(M,K) * B^T(N,K); A,B k-contiguous.
template<int BN, bool A_F32, bool B_F32>
__global__ __launch_bounds__(256) void mfma_gemm_nt(
    const void* __restrict__ Av, const void* __restrict__ Bv,
    float* __restrict__ C, int M, int N, int K,
    long long Abs, long long Bbs, long long Cbs)
{
    constexpr int BM = 128;
    constexpr int NFR = BN / 32;           // N-fragments per wave
    __shared__ __align__(16) ushort As[BM][40];
    __shared__ __align__(16) ushort Bs[BN][40];

    const int tid = threadIdx.x;
    const int m0 = blockIdx.x * BM;
    const int n0 = blockIdx.y * BN;
    const int b  = blockIdx.z;
    const int lane = tid & 63;
    const int wid  = tid >> 6;
    const int wr   = wid >> 1;
    const int wc   = wid & 1;
    const int fr   = lane & 15;
    const int kq   = lane >> 4;

    f32x4 acc[4][NFR];
    #pragma unroll
    for (int i = 0; i < 4; ++i)
        #pragma unroll
        for (int j = 0; j < NFR; ++j)
            acc[i][j] = (f32x4){0.f, 0.f, 0.f, 0.f};

    const int arow = tid >> 1;
    const int kh   = (tid & 1) * 16;

    for (int kt = 0; kt < K; kt += 32) {
        if (kt) __syncthreads();
        {
            const long long off = (long long)b * Abs + (long long)(m0 + arow) * K + kt + kh;
            us8 lo, hi;
            if (A_F32) {
                const float4* p = (const float4*)((const float*)Av + off);
                float4 v0 = p[0], v1 = p[1], v2 = p[2], v3 = p[3];
                lo = (us8){f2bf(v0.x), f2bf(v0.y), f2bf(v0.z), f2bf(v0.w),
                           f2bf(v1.x), f2bf(v1.y), f2bf(v1.z), f2bf(v1.w)};
                hi = (us8){f2bf(v2.x), f2bf(v2.y), f2bf(v2.z), f2bf(v2.w),
                           f2bf(v3.x), f2bf(v3.y), f2bf(v3.z), f2bf(v3.w)};
            } else {
                const us8* p = (const us8*)((const ushort*)Av + off);
                lo = p[0]; hi = p[1];
            }
            *(us8*)&As[arow][kh]     = lo;
            *(us8*)&As[arow][kh + 8] = hi;
        }
        if (BN == BM || arow < BN) {
            const long long off = (long long)b * Bbs + (long long)(n0 + arow) * K + kt + kh;
            us8 lo, hi;
            if (B_F32) {
                const float4* p = (const float4*)((const float*)Bv + off);
                float4 v0 = p[0], v1 = p[1], v2 = p[2], v3 = p[3];
                lo = (us8){f2bf(v0.x), f2bf(v0.y), f2bf(v0.z), f2bf(v0.w),
                           f2bf(v1.x), f2bf(v1.y), f2bf(v1.z), f2bf(v1.w)};
                hi = (us8){f2bf(v2.x), f2bf(v2.y), f2bf(v2.z), f2bf(v2.w),
                           f2bf(v3.x), f2bf(v3.y), f2bf(v3.z), f2bf(v3.w)};
            } else {
                const us8* p = (const us8*)((const ushort*)Bv + off);
                lo = p[0]; hi = p[1];
            }
            *(us8*)&Bs[arow][kh]     = lo;
            *(us8*)&Bs[arow][kh + 8] = hi;
        }
        __syncthreads();

        bf16x8 af[4], bfv[NFR];
        #pragma unroll
        for (int mi = 0; mi < 4; ++mi)
            af[mi] = *(const bf16x8*)&As[wr * 64 + mi * 16 + fr][kq * 8];
        #pragma unroll
        for (int ni = 0; ni < NFR; ++ni)
            bfv[ni] = *(const bf16x8*)&Bs[wc * (BN / 2) + ni * 16 + fr][kq * 8];
        #pragma unroll
        for (int mi = 0; mi < 4; ++mi)
            #pragma unroll
            for (int ni = 0; ni < NFR; ++ni)
                acc[mi][ni] = __builtin_amdgcn_mfma_f32_16x16x32_bf16(
                    af[mi], bfv[ni], acc[mi][ni], 0, 0, 0);
    }

    #pragma unroll
    for (int mi = 0; mi < 4; ++mi) {
        const int gm = m0 + wr * 64 + mi * 16 + kq * 4;
        #pragma unroll
        for (int ni = 0; ni < NFR; ++ni) {
            const int gn = n0 + wc * (BN / 2) + ni * 16 + fr;
            f32x4 v = acc[mi][ni];
            #pragma unroll
            for (int r = 0; r < 4; ++r)
                C[(long long)b * Cbs + (long long)(gm + r) * N + gn] = v[r];
        }
    }
}

// ---------------------------------------------------------------------------
// y (b, D, L) fp32 (batch stride Ybs) -> yt (b, L, D) bf16 (contiguous).
__global__ __launch_bounds__(256) void transpose_f32_bf16(
    const float* __restrict__ y, ushort* __restrict__ yt,
    int D, int Lx, long long Ybs)
{
    __shared__ float ts[32][33];
    const int l0 = blockIdx.x * 32, d0 = blockIdx.y * 32, b = blockIdx.z;
    const int tx = threadIdx.x & 31, ty = threadIdx.x >> 5;
    const float* yb = y + (size_t)b * Ybs + (size_t)d0 * Lx + l0;
    #pragma unroll
    for (int r = ty; r < 32; r += 8)
        ts[r][tx] = yb[(size_t)r * Lx + tx];
    __syncthreads();
    ushort* ytb = yt + ((size_t)b * Lx + l0) * D + d0;
    #pragma unroll
    for (int r = ty; r < 32; r += 8)
        ytb[(size_t)r * D + tx] = f2bf(ts[tx][r]);
}

// ---------------------------------------------------------------------------
// Generic tiled fp32 GEMM (small ops).
template<bool BKC, bool OUTM, bool CLIP, bool BIAS>
__global__ __launch_bounds__(256) void gemm_kernel(
    const float* __restrict__ A, const float* __restrict__ X,
    const float* __restrict__ bias, float* __restrict__ C,
    int M, int N, int K, long long Xbs, long long Cbs)
{
    __shared__ __align__(16) float As[16][68];
    __shared__ __align__(16) float Xs[16][68];
    const int m0 = blockIdx.x * 64;
    const int n0 = blockIdx.y * 64;
    const int b  = blockIdx.z;
    const float* Xb = X + (long long)b * Xbs;
    const int tid = threadIdx.x;
    const int te = tid & 15, tl = tid >> 4;
    float acc[4][4] = {};

    for (int k0 = 0; k0 < K; k0 += 16) {
        #pragma unroll
        for (int idx = tid; idx < 1024; idx += 256) {
            int e = idx >> 4, kk = idx & 15;
            int m = m0 + e, k = k0 + kk;
            As[kk][e] = (m < M && k < K) ? A[(long long)m * K + k] : 0.f;
        }
        if (BKC) {
            #pragma unroll
            for (int idx = tid; idx < 1024; idx += 256) {
                int n = idx >> 4, kk = idx & 15;
                int nn = n0 + n, k = k0 + kk;
                Xs[kk][n] = (nn < N && k < K) ? Xb[(long long)nn * K + k] : 0.f;
            }
        } else {
            #pragma unroll
            for (int idx = tid; idx < 1024; idx += 256) {
                int kk = idx >> 6, n = idx & 63;
                int nn = n0 + n, k = k0 + kk;
                Xs[kk][n] = (nn < N && k < K) ? Xb[(long long)k * N + nn] : 0.f;
            }
        }
        __syncthreads();
        #pragma unroll
        for (int kk = 0; kk < 16; ++kk) {
            float4 a4 = *reinterpret_cast<const float4*>(&As[kk][te * 4]);
            float4 x4 = *reinterpret_cast<const float4*>(&Xs[kk][tl * 4]);
            float av[4] = {a4.x, a4.y, a4.z, a4.w};
            float xv[4] = {x4.x, x4.y, x4.z, x4.w};
            #pragma unroll
            for (int i = 0; i < 4; ++i)
                #pragma unroll
                for (int j = 0; j < 4; ++j)
                    acc[i][j] += av[i] * xv[j];
        }
        __syncthreads();
    }

    #pragma unroll
    for (int i = 0; i < 4; ++i) {
        int m = m0 + te * 4 + i;
        if (m >= M) continue;
        float bv = BIAS ? bias[m] : 0.f;
        #pragma unroll
        for (int j = 0; j < 4; ++j) {
            int n = n0 + tl * 4 + j;
            if (n >= N) continue;
            float v = acc[i][j] + bv;
            if (CLIP) v = fminf(fmaxf(v, -6.f), 6.f);
            if (OUTM) C[(long long)b * Cbs + (long long)m * N + n] = v;
            else      C[(long long)b * Cbs + (long long)n * M + m] = v;
        }
    }
}

// ---------------------------------------------------------------------------
// Split-K NN GEMM: P[(b*KS+ks), m, n] = sum_{k in chunk ks} A[m,k]*X[b,k,n].
// X is (K,N) n-contiguous per batch. Partial slab stride = M*N.
__global__ __launch_bounds__(256) void gemm_nn_splitk(
    const float* __restrict__ A, const float* __restrict__ X,
    float* __restrict__ P, int M, int N, int K, int KS, long long Xbs)
{
    __shared__ __align__(16) float As[16][68];
    __shared__ __align__(16) float Xs[16][68];
    const int m0 = blockIdx.x * 64;
    const int n0 = blockIdx.y * 64;
    const int ks = blockIdx.z % KS;
    const int b  = blockIdx.z / KS;
    const int Kc = K / KS;
    const float* Xb = X + (long long)b * Xbs;
    const int tid = threadIdx.x;
    const int te = tid & 15, tl = tid >> 4;
    float acc[4][4] = {};

    for (int k0 = ks * Kc; k0 < (ks + 1) * Kc; k0 += 16) {
        #pragma unroll
        for (int idx = tid; idx < 1024; idx += 256) {
            int e = idx >> 4, kk = idx & 15;
            int m = m0 + e;
            As[kk][e] = (m < M) ? A[(long long)m * K + k0 + kk] : 0.f;
        }
        #pragma unroll
        for (int idx = tid; idx < 1024; idx += 256) {
            int kk = idx >> 6, n = idx & 63;
            Xs[kk][n] = Xb[(long long)(k0 + kk) * N + n0 + n];
        }
        __syncthreads();
        #pragma unroll
        for (int kk = 0; kk < 16; ++kk) {
            float4 a4 = *reinterpret_cast<const float4*>(&As[kk][te * 4]);
            float4 x4 = *reinterpret_cast<const float4*>(&Xs[kk][tl * 4]);
            float av[4] = {a4.x, a4.y, a4.z, a4.w};
            float xv[4] = {x4.x, x4.y, x4.z, x4.w};
            #pragma unroll
            for (int i = 0; i < 4; ++i)
                #pragma unroll
                for (int j = 0; j < 4; ++j)
                    acc[i][j] += av[i] * xv[j];
        }
        __syncthreads();
    }

    float* Pz = P + (long long)blockIdx.z * M * N;
    #pragma unroll
    for (int i = 0; i < 4; ++i) {
        int m = m0 + te * 4 + i;
        if (m >= M) continue;
        #pragma unroll
        for (int j = 0; j < 4; ++j)
            Pz[(long long)m * N + n0 + tl * 4 + j] = acc[i][j];
    }
}

// C[b][i] = sum_ks P[(b*KS+ks)*slab + i], float4-vectorized over slab.
__global__ __launch_bounds__(256) void reduce_splitk(
    const float* __restrict__ P, float* __restrict__ C, int slab, int KS)
{
    const int i4 = blockIdx.x * 256 + threadIdx.x;
    const int b  = blockIdx.y;
    if (i4 * 4 >= slab) return;
    const float* base = P + (size_t)b * KS * slab + (size_t)i4 * 4;
    float4 acc = make_float4(0.f, 0.f, 0.f, 0.f);
    for (int ks = 0; ks < KS; ++ks) {
        float4 v = *(const float4*)(base + (size_t)ks * slab);
        acc.x += v.x; acc.y += v.y; acc.z += v.z; acc.w += v.w;
    }
    *(float4*)(C + (size_t)b * slab + (size_t)i4 * 4) = acc;
}

// ---------------------------------------------------------------------------
__global__ __launch_bounds__(256) void conv_silu_kernel(
    const float* __restrict__ in, const float* __restrict__ w,
    const float* __restrict__ bias, float* __restrict__ out,
    int B, int D, int L, int W, int IC)
{
    int idx = blockIdx.x * 256 + threadIdx.x;
    int total = B * D * L;
    if (idx >= total) return;
    int l = idx % L;
    int d = (idx / L) % D;
    int b = idx / (L * D);
    const float* xp = in + (size_t)b * IC * L + (size_t)d * L;
    float acc = bias[d];
    for (int i = 0; i < W; ++i) {
        int li = l - (W - 1) + i;
        if (li >= 0) acc += w[d * W + i] * xp[li];
    }
    out[(size_t)b * D * L + (size_t)d * L + l] = siluf(acc);
}

// ---------------------------------------------------------------------------
// Chunked-parallel outer selective scan (2 ch x 8 chunks x 16 states / block).
__global__ __launch_bounds__(256) void scan_outer2_kernel(
    const float* __restrict__ delta, const float* __restrict__ u,
    const float* __restrict__ xz, const float* __restrict__ xdbl,
    const float* __restrict__ A_log, const float* __restrict__ Dp,
    const float* __restrict__ dt_bias, float* __restrict__ y,
    int Dch, int L, long long Ybs)
{
    __shared__ float2 dtdu[2][1024];
    __shared__ float2 PS[2][16][8];

    const int tid = threadIdx.x;
    const int b  = blockIdx.y;
    const int d0 = blockIdx.x * 2;

    {
        int ch = tid >> 7;
        int l0 = (tid & 127) * 8;
        int d  = d0 + ch;
        const float* dp = delta + ((size_t)b * Dch + d) * L + l0;
        const float* up = u     + ((size_t)b * Dch + d) * L + l0;
        float bias = dt_bias[d];
        float4 d4a = *(const float4*)(dp);
        float4 d4b = *(const float4*)(dp + 4);
        float4 u4a = *(const float4*)(up);
        float4 u4b = *(const float4*)(up + 4);
        float dv[8] = {d4a.x, d4a.y, d4a.z, d4a.w, d4b.x, d4b.y, d4b.z, d4b.w};
        float uv[8] = {u4a.x, u4a.y, u4a.z, u4a.w, u4b.x, u4b.y, u4b.z, u4b.w};
        #pragma unroll
        for (int t = 0; t < 8; ++t) {
            float dt = softplusf(dv[t] + bias);
            dtdu[ch][l0 + t] = make_float2(dt, dt * uv[t]);
        }
    }
    __syncthreads();

    const int ch = tid >> 7;
    const int t7 = tid & 127;
    const int c  = t7 >> 4;
    const int n  = t7 & 15;
    const int d  = d0 + ch;
    const float Adn = -__expf(A_log[d * 16 + n]);

    float s = 0.f, sumdt = 0.f;
    {
        const float* bp = xdbl + ((size_t)b * 96 + 64 + n) * L + c * 128;
        for (int q = 0; q < 32; ++q) {
            float4 b4 = *(const float4*)(bp + q * 4);
            float bv[4] = {b4.x, b4.y, b4.z, b4.w};
            #pragma unroll
            for (int t = 0; t < 4; ++t) {
                float2 dd = dtdu[ch][c * 128 + q * 4 + t];
                float a = __expf(dd.x * Adn);
                s = fmaf(a, s, dd.y * bv[t]);
                sumdt += dd.x;
            }
        }
    }
    PS[ch][n][c] = make_float2(__expf(sumdt * Adn), s);
    __syncthreads();

    float s0 = 0.f;
    for (int j = 0; j < c; ++j) {
        float2 ps = PS[ch][n][j];
        s0 = fmaf(ps.x, s0, ps.y);
    }

    {
        const size_t ubase = ((size_t)b * Dch + d) * L + (size_t)c * 128;
        const size_t ybase = (size_t)b * Ybs + (size_t)d * L + (size_t)c * 128;
        const float* bp = xdbl + ((size_t)b * 96 + 64 + n) * L + c * 128;
        const float* cp = xdbl + ((size_t)b * 96 + 80 + n) * L + c * 128;
        const float* up = u + ubase;
        const float* zp = xz + ((size_t)b * 2 * Dch + Dch + d) * L + c * 128;
        const float Dd = Dp[d];
        float s2 = s0;
        for (int q = 0; q < 32; ++q) {
            float4 b4 = *(const float4*)(bp + q * 4);
            float4 c4 = *(const float4*)(cp + q * 4);
            float4 u4 = *(const float4*)(up + q * 4);
            float4 z4 = *(const float4*)(zp + q * 4);
            float bv[4] = {b4.x, b4.y, b4.z, b4.w};
            float cv[4] = {c4.x, c4.y, c4.z, c4.w};
            float uv[4] = {u4.x, u4.y, u4.z, u4.w};
            float zv[4] = {z4.x, z4.y, z4.z, z4.w};
            float yv[4];
            #pragma unroll
            for (int t = 0; t < 4; ++t) {
                float2 dd = dtdu[ch][c * 128 + q * 4 + t];
                float a = __expf(dd.x * Adn);
                s2 = fmaf(a, s2, dd.y * bv[t]);
                float p = s2 * cv[t];
                p += __shfl_xor(p, 1, 16);
                p += __shfl_xor(p, 2, 16);
                p += __shfl_xor(p, 4, 16);
                p += __shfl_xor(p, 8, 16);
                yv[t] = (p + Dd * uv[t]) * siluf(zv[t]);
            }
            if (n == 0)
                *(float4*)(y + ybase + q * 4) = make_float4(yv[0], yv[1], yv[2], yv[3]);
        }
    }
}

// ---------------------------------------------------------------------------
// Chunked-parallel inner selective scan.
__global__ __launch_bounds__(256) void scan_inner2_kernel(
    const float* __restrict__ mdelta, const float* __restrict__ mu,
    const float* __restrict__ mxz, const float* __restrict__ mxdbl,
    const float* __restrict__ mA_log, const float* __restrict__ mDp,
    const float* __restrict__ mdt_b, float* __restrict__ ym, int L)
{
    __shared__ float2 dtdu[1024];
    __shared__ float2 PS[4][64];

    const int tid = threadIdx.x;
    const int b = blockIdx.y;
    const int d = blockIdx.x;
    const size_t base = ((size_t)b * 64 + d) * L;

    {
        int l0 = tid * 4;
        float4 d4 = *(const float4*)(mdelta + base + l0);
        float4 u4 = *(const float4*)(mu + base + l0);
        float bias = mdt_b[d];
        float dv[4] = {d4.x, d4.y, d4.z, d4.w};
        float uv[4] = {u4.x, u4.y, u4.z, u4.w};
        #pragma unroll
        for (int t = 0; t < 4; ++t) {
            float dt = softplusf(dv[t] + bias);
            dtdu[l0 + t] = make_float2(dt, dt * uv[t]);
        }
    }
    __syncthreads();

    const int c = tid >> 2;
    const int n = tid & 3;
    const float Adn = -__expf(mA_log[d * 4 + n]);

    float s = 0.f, sumdt = 0.f;
    {
        const float* bp = mxdbl + ((size_t)b * 12 + 4 + n) * L + c * 16;
        for (int q = 0; q < 4; ++q) {
            float4 b4 = *(const float4*)(bp + q * 4);
            float bv[4] = {b4.x, b4.y, b4.z, b4.w};
            #pragma unroll
            for (int t = 0; t < 4; ++t) {
                float2 dd = dtdu[c * 16 + q * 4 + t];
                float a = __expf(dd.x * Adn);
                s = fmaf(a, s, dd.y * bv[t]);
                sumdt += dd.x;
            }
        }
    }
    PS[n][c] = make_float2(__expf(sumdt * Adn), s);
    __syncthreads();

    float s0 = 0.f;
    for (int j = 0; j < c; ++j) {
        float2 ps = PS[n][j];
        s0 = fmaf(ps.x, s0, ps.y);
    }

    {
        const float* bp = mxdbl + ((size_t)b * 12 + 4 + n) * L + c * 16;
        const float* cp = mxdbl + ((size_t)b * 12 + 8 + n) * L + c * 16;
        const float* up = mu + base + c * 16;
        const float* zp = mxz + ((size_t)b * 128 + 64 + d) * L + c * 16;
        const float Dd = mDp[d];
        float s2 = s0;
        for (int q = 0; q < 4; ++q) {
            float4 b4 = *(const float4*)(bp + q * 4);
            float4 c4 = *(const float4*)(cp + q * 4);
            float4 u4 = *(const float4*)(up + q * 4);
            float4 z4 = *(const float4*)(zp + q * 4);
            float bv[4] = {b4.x, b4.y, b4.z, b4.w};
            float cv[4] = {c4.x, c4.y, c4.z, c4.w};
            float uv[4] = {u4.x, u4.y, u4.z, u4.w};
            float zv[4] = {z4.x, z4.y, z4.z, z4.w};
            float yv[4];
            #pragma unroll
            for (int t = 0; t < 4; ++t) {
                float2 dd = dtdu[c * 16 + q * 4 + t];
                float a = __expf(dd.x * Adn);
                s2 = fmaf(a, s2, dd.y * bv[t]);
                float p = s2 * cv[t];
                p += __shfl_xor(p, 1, 4);
                p += __shfl_xor(p, 2, 4);
                yv[t] = (p + Dd * uv[t]) * siluf(zv[t]);
            }
            if (n == 0)
                *(float4*)(ym + base + c * 16 + q * 4) = make_float4(yv[0], yv[1], yv[2], yv[3]);
        }
    }
}

// ---------------------------------------------------------------------------
extern "C" void kernel_launch(void* const* d_in, const int* in_sizes, int n_in,
                              void* d_out, int out_size, void* d_ws, size_t ws_size,
                              hipStream_t stream)
{
    const float* h         = (const float*)d_in[0];
    const float* in_w      = (const float*)d_in[1];
    const float* conv_w    = (const float*)d_in[2];
    const float* conv_b    = (const float*)d_in[3];
    const float* xproj_w   = (const float*)d_in[4];
    const float* dt_out_w  = (const float*)d_in[5];
    const float* dt_out_b  = (const float*)d_in[6];
    const float* A_log     = (const float*)d_in[7];
    const float* Dp        = (const float*)d_in[8];
    const float* out_w     = (const float*)d_in[9];
    const float* m_in_w    = (const float*)d_in[10];
    const float* m_conv_w  = (const float*)d_in[11];
    const float* m_conv_b  = (const float*)d_in[12];
    const float* m_xproj_w = (const float*)d_in[13];
    const float* m_dt_w    = (const float*)d_in[14];
    const float* m_dt_b    = (const float*)d_in[15];
    const float* m_A_log   = (const float*)d_in[16];
    const float* m_Dp      = (const float*)d_in[17];
    const float* m_out_w   = (const float*)d_in[18];
    float* out = (float*)d_out;

    const int B = 2, L = 1024, dm = 1024, di = 2048;

    float* ws     = (float*)d_ws;
    float* xz     = ws;                              // B*4096*L (x-rows reused as y)
    float* xconv  = xz     + (size_t)B * 2 * di * L; // B*2048*L
    float* xdbl   = xconv  + (size_t)B * di * L;     // B*96*L
    float* mxz    = xdbl   + (size_t)B * 96 * L;     // B*128*L
    float* mxconv = mxz    + (size_t)B * 128 * L;    // B*64*L
    float* mxdbl  = mxconv + (size_t)B * 64 * L;     // B*12*L
    float* mdelta = mxdbl  + (size_t)B * 12 * L;     // B*64*L
    float* ym     = mdelta + (size_t)B * 64 * L;     // B*64*L
    float* dtm    = ym     + (size_t)B * 64 * L;     // B*64*L
    float* delta  = dtm    + (size_t)B * 64 * L;     // B*2048*L
    ushort* yt    = (ushort*)delta;                  // bf16 y^T (after scan)
    float* part   = delta;                           // split-K partials (before step 10)

    dim3 blk(256);

    // 1. xz[b,e,l] = sum_d in_w[e,d]*h[b,l,d]   (bf16 MFMA NT, fp32 out)
    mfma_gemm_nt<128, true, true><<<dim3(4096 / 128, L / 128, B), blk, 0, stream>>>(
        in_w, h, xz, 2 * di, L, dm, 0LL, (long long)L * dm, (long long)2 * di * L);

    // 2. x = silu(causal_conv(xz[:, :di]))
    {
        int total = B * di * L;
        conv_silu_kernel<<<dim3((total + 255) / 256), blk, 0, stream>>>(
            xz, conv_w, conv_b, xconv, B, di, L, 4, 2 * di);
    }

    // 3. xdbl[b,e,l] = sum_d xproj_w[e,d]*xconv[b,d,l]  (split-K=16, partials
    //    in the dead delta region, then deterministic reduce)
    {
        const int KS = 16;
        gemm_nn_splitk<<<dim3(2, 16, B * KS), blk, 0, stream>>>(
            xproj_w, xconv, part, 96, L, di, KS, (long long)di * L);
        int slab = 96 * L;
        reduce_splitk<<<dim3((slab / 4 + 255) / 256, B), blk, 0, stream>>>(
            part, xdbl, slab, KS);
    }

    // 4. inner in_proj
    gemm_kernel<false, true, false, false><<<dim3(2, 16, B), blk, 0, stream>>>(
        m_in_w, xdbl, nullptr, mxz, 128, L, 64, (long long)96 * L, (long long)128 * L);

    // 5. inner conv+silu (width 2)
    {
        int total = B * 64 * L;
        conv_silu_kernel<<<dim3((total + 255) / 256), blk, 0, stream>>>(
            mxz, m_conv_w, m_conv_b, mxconv, B, 64, L, 2, 128);
    }

    // 6. inner x_proj
    gemm_kernel<false, true, false, false><<<dim3(1, 16, B), blk, 0, stream>>>(
        m_xproj_w, mxconv, nullptr, mxdbl, 12, L, 64, (long long)64 * L, (long long)12 * L);

    // 7. inner delta
    gemm_kernel<false, true, false, false><<<dim3(1, 16, B), blk, 0, stream>>>(
        m_dt_w, mxdbl, nullptr, mdelta, 64, L, 4, (long long)12 * L, (long long)64 * L);

    // 8. inner selective scan -> ym
    scan_inner2_kernel<<<dim3(64, B), blk, 0, stream>>>(
        mdelta, mxconv, mxz, mxdbl, m_A_log, m_Dp, m_dt_b, ym, L);

    // 9. inner out_proj
    gemm_kernel<false, true, false, false><<<dim3(1, 16, B), blk, 0, stream>>>(
        m_out_w, ym, nullptr, dtm, 64, L, 64, (long long)64 * L, (long long)64 * L);

    // 10. delta = clip(dt_out_w @ dtm + dt_out_b, +-6)   (overwrites partials)
    gemm_kernel<false, true, true, true><<<dim3(32, 16, B), blk, 0, stream>>>(
        dt_out_w, dtm, dt_out_b, delta, di, L, 64, (long long)64 * L, (long long)di * L);

    // 11. outer selective scan -> y into the dead x-rows of xz (fp32)
    scan_outer2_kernel<<<dim3(di / 2, B), blk, 0, stream>>>(
        delta, xconv, xz, xdbl, A_log, Dp, dt_out_b, xz, di, L, (long long)2 * di * L);

    // 11b. y (b,di,L in xz rows) -> yt (b,L,di) bf16 (delta buffer dead again)
    transpose_f32_bf16<<<dim3(L / 32, di / 32, B), blk, 0, stream>>>(
        xz, yt, di, L, (long long)2 * di * L);

    // 12. out[(b,l),e] = sum_d yt[(b,l),d]*out_w[e,d]  (batch-merged M=2048)
    mfma_gemm_nt<64, false, true><<<dim3(B * L / 128, dm / 64, 1), blk, 0, stream>>>(
        yt, out_w, out, B * L, dm, di, 0LL, 0LL, 0LL);
}

// Round 6
// 392.187 us; speedup vs baseline: 5.7393x; 1.0264x over previous
//
#include <hip/hip_runtime.h>
#include <hip/hip_bf16.h>

#define DEVFN __device__ __forceinline__

DEVFN float siluf(float x)     { return x / (1.f + __expf(-x)); }
DEVFN float softplusf(float x) { return fmaxf(x, 0.f) + log1pf(__expf(-fabsf(x))); }

DEVFN ushort f2bf(float f) {               // RNE fp32 -> bf16
    union { float f; unsigned u; } v; v.f = f;
    unsigned r = (v.u + 0x7FFF + ((v.u >> 16) & 1)) >> 16;
    return (ushort)r;
}

// DPP cross-lane add: x + lane_perm(x). CTRL: 0x128=row_ror:8, 0x124=row_ror:4,
// 0x4E=quad_perm[2,3,0,1] (xor2), 0xB1=quad_perm[1,0,3,2] (xor1).
template<int CTRL>
DEVFN float dpp_addf(float x) {
    union { float f; int i; } a, r;
    a.f = x;
    r.i = __builtin_amdgcn_update_dpp(0, a.i, CTRL, 0xF, 0xF, true);
    return x + r.f;
}
DEVFN float sum16(float p) {   // sum across 16-lane row, result in all lanes
    p = dpp_addf<0x128>(p);
    p = dpp_addf<0x124>(p);
    p = dpp_addf<0x4E>(p);
    p = dpp_addf<0xB1>(p);
    return p;
}
DEVFN float sum4(float p) {    // sum across 4-lane quad
    p = dpp_addf<0x4E>(p);
    p = dpp_addf<0xB1>(p);
    return p;
}

typedef __bf16 bf16x8 __attribute__((ext_vector_type(8)));
typedef float  f32x4  __attribute__((ext_vector_type(4)));
typedef ushort us8    __attribute__((ext_vector_type(8)));

// ---------------------------------------------------------------------------
// bf16 MFMA NT GEMM: C(M,N) += A(M,K) * B^T(N,K); A,B k-contiguous.
template<int BN, bool A_F32, bool B_F32>
__global__ __launch_bounds__(256) void mfma_gemm_nt(
    const void* __restrict__ Av, const void* __restrict__ Bv,
    float* __restrict__ C, int M, int N, int K,
    long long Abs, long long Bbs, long long Cbs)
{
    constexpr int BM = 128;
    constexpr int NFR = BN / 32;
    __shared__ __align__(16) ushort As[BM][40];
    __shared__ __align__(16) ushort Bs[BN][40];

    const int tid = threadIdx.x;
    const int m0 = blockIdx.x * BM;
    const int n0 = blockIdx.y * BN;
    const int b  = blockIdx.z;
    const int lane = tid & 63;
    const int wid  = tid >> 6;
    const int wr   = wid >> 1;
    const int wc   = wid & 1;
    const int fr   = lane & 15;
    const int kq   = lane >> 4;

    f32x4 acc[4][NFR];
    #pragma unroll
    for (int i = 0; i < 4; ++i)
        #pragma unroll
        for (int j = 0; j < NFR; ++j)
            acc[i][j] = (f32x4){0.f, 0.f, 0.f, 0.f};

    const int arow = tid >> 1;
    const int kh   = (tid & 1) * 16;

    for (int kt = 0; kt < K; kt += 32) {
        if (kt) __syncthreads();
        {
            const long long off = (long long)b * Abs + (long long)(m0 + arow) * K + kt + kh;
            us8 lo, hi;
            if (A_F32) {
                const float4* p = (const float4*)((const float*)Av + off);
                float4 v0 = p[0], v1 = p[1], v2 = p[2], v3 = p[3];
                lo = (us8){f2bf(v0.x), f2bf(v0.y), f2bf(v0.z), f2bf(v0.w),
                           f2bf(v1.x), f2bf(v1.y), f2bf(v1.z), f2bf(v1.w)};
                hi = (us8){f2bf(v2.x), f2bf(v2.y), f2bf(v2.z), f2bf(v2.w),
                           f2bf(v3.x), f2bf(v3.y), f2bf(v3.z), f2bf(v3.w)};
            } else {
                const us8* p = (const us8*)((const ushort*)Av + off);
                lo = p[0]; hi = p[1];
            }
            *(us8*)&As[arow][kh]     = lo;
            *(us8*)&As[arow][kh + 8] = hi;
        }
        if (BN == BM || arow < BN) {
            const long long off = (long long)b * Bbs + (long long)(n0 + arow) * K + kt + kh;
            us8 lo, hi;
            if (B_F32) {
                const float4* p = (const float4*)((const float*)Bv + off);
                float4 v0 = p[0], v1 = p[1], v2 = p[2], v3 = p[3];
                lo = (us8){f2bf(v0.x), f2bf(v0.y), f2bf(v0.z), f2bf(v0.w),
                           f2bf(v1.x), f2bf(v1.y), f2bf(v1.z), f2bf(v1.w)};
                hi = (us8){f2bf(v2.x), f2bf(v2.y), f2bf(v2.z), f2bf(v2.w),
                           f2bf(v3.x), f2bf(v3.y), f2bf(v3.z), f2bf(v3.w)};
            } else {
                const us8* p = (const us8*)((const ushort*)Bv + off);
                lo = p[0]; hi = p[1];
            }
            *(us8*)&Bs[arow][kh]     = lo;
            *(us8*)&Bs[arow][kh + 8] = hi;
        }
        __syncthreads();

        bf16x8 af[4], bfv[NFR];
        #pragma unroll
        for (int mi = 0; mi < 4; ++mi)
            af[mi] = *(const bf16x8*)&As[wr * 64 + mi * 16 + fr][kq * 8];
        #pragma unroll
        for (int ni = 0; ni < NFR; ++ni)
            bfv[ni] = *(const bf16x8*)&Bs[wc * (BN / 2) + ni * 16 + fr][kq * 8];
        #pragma unroll
        for (int mi = 0; mi < 4; ++mi)
            #pragma unroll
            for (int ni = 0; ni < NFR; ++ni)
                acc[mi][ni] = __builtin_amdgcn_mfma_f32_16x16x32_bf16(
                    af[mi], bfv[ni], acc[mi][ni], 0, 0, 0);
    }

    #pragma unroll
    for (int mi = 0; mi < 4; ++mi) {
        const int gm = m0 + wr * 64 + mi * 16 + kq * 4;
        #pragma unroll
        for (int ni = 0; ni < NFR; ++ni) {
            const int gn = n0 + wc * (BN / 2) + ni * 16 + fr;
            f32x4 v = acc[mi][ni];
            #pragma unroll
            for (int r = 0; r < 4; ++r)
                C[(long long)b * Cbs + (long long)(gm + r) * N + gn] = v[r];
        }
    }
}

// ---------------------------------------------------------------------------
// y (b, D, L) fp32 (batch stride Ybs) -> yt (b, L, D) bf16 (contiguous).
__global__ __launch_bounds__(256) void transpose_f32_bf16(
    const float* __restrict__ y, ushort* __restrict__ yt,
    int D, int Lx, long long Ybs)
{
    __shared__ float ts[32][33];
    const int l0 = blockIdx.x * 32, d0 = blockIdx.y * 32, b = blockIdx.z;
    const int tx = threadIdx.x & 31, ty = threadIdx.x >> 5;
    const float* yb = y + (size_t)b * Ybs + (size_t)d0 * Lx + l0;
    #pragma unroll
    for (int r = ty; r < 32; r += 8)
        ts[r][tx] = yb[(size_t)r * Lx + tx];
    __syncthreads();
    ushort* ytb = yt + ((size_t)b * Lx + l0) * D + d0;
    #pragma unroll
    for (int r = ty; r < 32; r += 8)
        ytb[(size_t)r * D + tx] = f2bf(ts[tx][r]);
}

// ---------------------------------------------------------------------------
// Generic tiled fp32 GEMM (small ops).
template<bool BKC, bool OUTM, bool CLIP, bool BIAS>
__global__ __launch_bounds__(256) void gemm_kernel(
    const float* __restrict__ A, const float* __restrict__ X,
    const float* __restrict__ bias, float* __restrict__ C,
    int M, int N, int K, long long Xbs, long long Cbs)
{
    __shared__ __align__(16) float As[16][68];
    __shared__ __align__(16) float Xs[16][68];
    const int m0 = blockIdx.x * 64;
    const int n0 = blockIdx.y * 64;
    const int b  = blockIdx.z;
    const float* Xb = X + (long long)b * Xbs;
    const int tid = threadIdx.x;
    const int te = tid & 15, tl = tid >> 4;
    float acc[4][4] = {};

    for (int k0 = 0; k0 < K; k0 += 16) {
        #pragma unroll
        for (int idx = tid; idx < 1024; idx += 256) {
            int e = idx >> 4, kk = idx & 15;
            int m = m0 + e, k = k0 + kk;
            As[kk][e] = (m < M && k < K) ? A[(long long)m * K + k] : 0.f;
        }
        if (BKC) {
            #pragma unroll
            for (int idx = tid; idx < 1024; idx += 256) {
                int n = idx >> 4, kk = idx & 15;
                int nn = n0 + n, k = k0 + kk;
                Xs[kk][n] = (nn < N && k < K) ? Xb[(long long)nn * K + k] : 0.f;
            }
        } else {
            #pragma unroll
            for (int idx = tid; idx < 1024; idx += 256) {
                int kk = idx >> 6, n = idx & 63;
                int nn = n0 + n, k = k0 + kk;
                Xs[kk][n] = (nn < N && k < K) ? Xb[(long long)k * N + nn] : 0.f;
            }
        }
        __syncthreads();
        #pragma unroll
        for (int kk = 0; kk < 16; ++kk) {
            float4 a4 = *reinterpret_cast<const float4*>(&As[kk][te * 4]);
            float4 x4 = *reinterpret_cast<const float4*>(&Xs[kk][tl * 4]);
            float av[4] = {a4.x, a4.y, a4.z, a4.w};
            float xv[4] = {x4.x, x4.y, x4.z, x4.w};
            #pragma unroll
            for (int i = 0; i < 4; ++i)
                #pragma unroll
                for (int j = 0; j < 4; ++j)
                    acc[i][j] += av[i] * xv[j];
        }
        __syncthreads();
    }

    #pragma unroll
    for (int i = 0; i < 4; ++i) {
        int m = m0 + te * 4 + i;
        if (m >= M) continue;
        float bv = BIAS ? bias[m] : 0.f;
        #pragma unroll
        for (int j = 0; j < 4; ++j) {
            int n = n0 + tl * 4 + j;
            if (n >= N) continue;
            float v = acc[i][j] + bv;
            if (CLIP) v = fminf(fmaxf(v, -6.f), 6.f);
            if (OUTM) C[(long long)b * Cbs + (long long)m * N + n] = v;
            else      C[(long long)b * Cbs + (long long)n * M + m] = v;
        }
    }
}

// ---------------------------------------------------------------------------
// Split-K NN GEMM: P[(b*KS+ks), m, n] = sum_{k in chunk ks} A[m,k]*X[b,k,n].
__global__ __launch_bounds__(256) void gemm_nn_splitk(
    const float* __restrict__ A, const float* __restrict__ X,
    float* __restrict__ P, int M, int N, int K, int KS, long long Xbs)
{
    __shared__ __align__(16) float As[16][68];
    __shared__ __align__(16) float Xs[16][68];
    const int m0 = blockIdx.x * 64;
    const int n0 = blockIdx.y * 64;
    const int ks = blockIdx.z % KS;
    const int b  = blockIdx.z / KS;
    const int Kc = K / KS;
    const float* Xb = X + (long long)b * Xbs;
    const int tid = threadIdx.x;
    const int te = tid & 15, tl = tid >> 4;
    float acc[4][4] = {};

    for (int k0 = ks * Kc; k0 < (ks + 1) * Kc; k0 += 16) {
        #pragma unroll
        for (int idx = tid; idx < 1024; idx += 256) {
            int e = idx >> 4, kk = idx & 15;
            int m = m0 + e;
            As[kk][e] = (m < M) ? A[(long long)m * K + k0 + kk] : 0.f;
        }
        #pragma unroll
        for (int idx = tid; idx < 1024; idx += 256) {
            int kk = idx >> 6, n = idx & 63;
            Xs[kk][n] = Xb[(long long)(k0 + kk) * N + n0 + n];
        }
        __syncthreads();
        #pragma unroll
        for (int kk = 0; kk < 16; ++kk) {
            float4 a4 = *reinterpret_cast<const float4*>(&As[kk][te * 4]);
            float4 x4 = *reinterpret_cast<const float4*>(&Xs[kk][tl * 4]);
            float av[4] = {a4.x, a4.y, a4.z, a4.w};
            float xv[4] = {x4.x, x4.y, x4.z, x4.w};
            #pragma unroll
            for (int i = 0; i < 4; ++i)
                #pragma unroll
                for (int j = 0; j < 4; ++j)
                    acc[i][j] += av[i] * xv[j];
        }
        __syncthreads();
    }

    float* Pz = P + (long long)blockIdx.z * M * N;
    #pragma unroll
    for (int i = 0; i < 4; ++i) {
        int m = m0 + te * 4 + i;
        if (m >= M) continue;
        #pragma unroll
        for (int j = 0; j < 4; ++j)
            Pz[(long long)m * N + n0 + tl * 4 + j] = acc[i][j];
    }
}

__global__ __launch_bounds__(256) void reduce_splitk(
    const float* __restrict__ P, float* __restrict__ C, int slab, int KS)
{
    const int i4 = blockIdx.x * 256 + threadIdx.x;
    const int b  = blockIdx.y;
    if (i4 * 4 >= slab) return;
    const float* base = P + (size_t)b * KS * slab + (size_t)i4 * 4;
    float4 acc = make_float4(0.f, 0.f, 0.f, 0.f);
    for (int ks = 0; ks < KS; ++ks) {
        float4 v = *(const float4*)(base + (size_t)ks * slab);
        acc.x += v.x; acc.y += v.y; acc.z += v.z; acc.w += v.w;
    }
    *(float4*)(C + (size_t)b * slab + (size_t)i4 * 4) = acc;
}

// ---------------------------------------------------------------------------
// Vectorized causal depthwise conv W=4 + SiLU, 4 outputs/thread.
__global__ __launch_bounds__(256) void conv4_silu_kernel(
    const float* __restrict__ in, const float* __restrict__ w,
    const float* __restrict__ bias, float* __restrict__ out,
    int B, int D, int L, int IC)
{
    int idx = blockIdx.x * 256 + threadIdx.x;
    int nL4 = L >> 2;
    if (idx >= B * D * nL4) return;
    int l4 = (idx % nL4) * 4;
    int d  = (idx / nL4) % D;
    int b  = idx / (nL4 * D);
    const float* xp = in + ((size_t)b * IC + d) * L;
    float4 cur = *(const float4*)(xp + l4);
    float4 prev = make_float4(0.f, 0.f, 0.f, 0.f);
    if (l4) prev = *(const float4*)(xp + l4 - 4);
    const float4 wv = *(const float4*)(w + d * 4);
    float bv = bias[d];
    float y0 = bv + wv.x*prev.y + wv.y*prev.z + wv.z*prev.w + wv.w*cur.x;
    float y1 = bv + wv.x*prev.z + wv.y*prev.w + wv.z*cur.x  + wv.w*cur.y;
    float y2 = bv + wv.x*prev.w + wv.y*cur.x  + wv.z*cur.y  + wv.w*cur.z;
    float y3 = bv + wv.x*cur.x  + wv.y*cur.y  + wv.z*cur.z  + wv.w*cur.w;
    *(float4*)(out + ((size_t)b * D + d) * L + l4) =
        make_float4(siluf(y0), siluf(y1), siluf(y2), siluf(y3));
}

// Scalar causal conv (inner, W=2) + SiLU.
__global__ __launch_bounds__(256) void conv_silu_kernel(
    const float* __restrict__ in, const float* __restrict__ w,
    const float* __restrict__ bias, float* __restrict__ out,
    int B, int D, int L, int W, int IC)
{
    int idx = blockIdx.x * 256 + threadIdx.x;
    int total = B * D * L;
    if (idx >= total) return;
    int l = idx % L;
    int d = (idx / L) % D;
    int b = idx / (L * D);
    const float* xp = in + (size_t)b * IC * L + (size_t)d * L;
    float acc = bias[d];
    for (int i = 0; i < W; ++i) {
        int li = l - (W - 1) + i;
        if (li >= 0) acc += w[d * W + i] * xp[li];
    }
    out[(size_t)b * D * L + (size_t)d * L + l] = siluf(acc);
}

// ---------------------------------------------------------------------------
// Fused inner x_proj + dt matmuls: mxdbl(12,L) and mdelta(64,L) per batch.
// Grid (L/64, B), 256 threads.
__global__ __launch_bounds__(256) void inner_xproj_dt_kernel(
    const float* __restrict__ mxconv, const float* __restrict__ xw,
    const float* __restrict__ dtw, float* __restrict__ mxdbl,
    float* __restrict__ mdelta, int L)
{
    __shared__ float xs[64][65];
    __shared__ float xwl[12][64];
    __shared__ float dtl[64][4];
    __shared__ float xd[4][65];
    const int tid = threadIdx.x;
    const int l0 = blockIdx.x * 64;
    const int b  = blockIdx.y;

    for (int o = tid; o < 4096; o += 256) {
        int k = o >> 6, l = o & 63;
        xs[k][l] = mxconv[((size_t)b * 64 + k) * L + l0 + l];
    }
    if (tid < 768) xwl[tid >> 6][tid & 63] = xw[tid];
    dtl[tid >> 2][tid & 3] = dtw[tid];
    __syncthreads();

    for (int o = tid; o < 768; o += 256) {
        int e = o >> 6, l = o & 63;
        float acc = 0.f;
        #pragma unroll
        for (int k = 0; k < 64; ++k) acc += xwl[e][k] * xs[k][l];
        mxdbl[((size_t)b * 12 + e) * L + l0 + l] = acc;
        if (e < 4) xd[e][l] = acc;
    }
    __syncthreads();

    for (int o = tid; o < 4096; o += 256) {
        int dch = o >> 6, l = o & 63;
        float acc = dtl[dch][0] * xd[0][l] + dtl[dch][1] * xd[1][l]
                  + dtl[dch][2] * xd[2][l] + dtl[dch][3] * xd[3][l];
        mdelta[((size_t)b * 64 + dch) * L + l0 + l] = acc;
    }
}

// ---------------------------------------------------------------------------
// Outer selective scan v3: 1 channel/block, 16 chunks x 16 states, 64 steps
// per chunk, DPP lane reductions, padded LDS. Grid (Dch, B).
__global__ __launch_bounds__(256) void scan_outer3_kernel(
    const float* __restrict__ delta, const float* __restrict__ u,
    const float* __restrict__ xz, const float* __restrict__ xdbl,
    const float* __restrict__ A_log, const float* __restrict__ Dp,
    const float* __restrict__ dt_bias, float* __restrict__ y,
    int Dch, int L, long long Ybs)
{
    __shared__ float2 dtdu[16][66];    // [chunk][step] padded vs bank aliasing
    __shared__ float2 PS[16][17];      // [state][chunk]

    const int tid = threadIdx.x;
    const int b = blockIdx.y;
    const int d = blockIdx.x;
    const size_t rbase = ((size_t)b * Dch + d) * L;

    // phase 0: dt/dt*u for the whole row (4 l's per thread)
    {
        const int l0 = tid * 4;
        float4 d4 = *(const float4*)(delta + rbase + l0);
        float4 u4 = *(const float4*)(u + rbase + l0);
        float bias = dt_bias[d];
        float dv[4] = {d4.x, d4.y, d4.z, d4.w};
        float uv[4] = {u4.x, u4.y, u4.z, u4.w};
        #pragma unroll
        for (int t = 0; t < 4; ++t) {
            float dt = softplusf(dv[t] + bias);
            dtdu[tid >> 4][(tid & 15) * 4 + t] = make_float2(dt, dt * uv[t]);
        }
    }
    __syncthreads();

    const int c = tid >> 4;            // chunk 0..15 (64 steps)
    const int n = tid & 15;            // state
    const float Adn = -__expf(A_log[d * 16 + n]);

    // phase 1: chunk-local scan
    float s = 0.f, sumdt = 0.f;
    {
        const float* bp = xdbl + ((size_t)b * 96 + 64 + n) * L + c * 64;
        for (int q = 0; q < 16; ++q) {
            float4 b4 = *(const float4*)(bp + q * 4);
            float bv[4] = {b4.x, b4.y, b4.z, b4.w};
            #pragma unroll
            for (int t = 0; t < 4; ++t) {
                float2 dd = dtdu[c][q * 4 + t];
                float a = __expf(dd.x * Adn);
                s = fmaf(a, s, dd.y * bv[t]);
                sumdt += dd.x;
            }
        }
    }
    PS[n][c] = make_float2(__expf(sumdt * Adn), s);
    __syncthreads();

    // chunk-initial state: serial fold over previous chunks
    float s0 = 0.f;
    for (int j = 0; j < c; ++j) {
        float2 ps = PS[n][j];
        s0 = fmaf(ps.x, s0, ps.y);
    }

    // phase 2: rescan with init, DPP-reduce over states, emit y
    {
        const size_t ybase = (size_t)b * Ybs + (size_t)d * L + (size_t)c * 64;
        const float* bp = xdbl + ((size_t)b * 96 + 64 + n) * L + c * 64;
        const float* cp = xdbl + ((size_t)b * 96 + 80 + n) * L + c * 64;
        const float* up = u + rbase + (size_t)c * 64;
        const float* zp = xz + ((size_t)b * 2 * Dch + Dch + d) * L + c * 64;
        const float Dd = Dp[d];
        float s2 = s0;
        for (int q = 0; q < 16; ++q) {
            float4 b4 = *(const float4*)(bp + q * 4);
            float4 c4 = *(const float4*)(cp + q * 4);
            float4 u4 = *(const float4*)(up + q * 4);
            float4 z4 = *(const float4*)(zp + q * 4);
            float bv[4] = {b4.x, b4.y, b4.z, b4.w};
            float cv[4] = {c4.x, c4.y, c4.z, c4.w};
            float uv[4] = {u4.x, u4.y, u4.z, u4.w};
            float zv[4] = {z4.x, z4.y, z4.z, z4.w};
            float yv[4];
            #pragma unroll
            for (int t = 0; t < 4; ++t) {
                float2 dd = dtdu[c][q * 4 + t];
                float a = __expf(dd.x * Adn);
                s2 = fmaf(a, s2, dd.y * bv[t]);
                float p = sum16(s2 * cv[t]);
                yv[t] = (p + Dd * uv[t]) * siluf(zv[t]);
            }
            if (n == 0)
                *(float4*)(y + ybase + q * 4) = make_float4(yv[0], yv[1], yv[2], yv[3]);
        }
    }
}

// ---------------------------------------------------------------------------
// Inner selective scan v3: 64 chunks x 4 states, DPP quad reductions.
__global__ __launch_bounds__(256) void scan_inner3_kernel(
    const float* __restrict__ mdelta, const float* __restrict__ mu,
    const float* __restrict__ mxz, const float* __restrict__ mxdbl,
    const float* __restrict__ mA_log, const float* __restrict__ mDp,
    const float* __restrict__ mdt_b, float* __restrict__ ym, int L)
{
    __shared__ float2 dtdu[64][17];    // [chunk][step] padded
    __shared__ float2 PS[4][66];       // [state][chunk] padded

    const int tid = threadIdx.x;
    const int b = blockIdx.y;
    const int d = blockIdx.x;
    const size_t base = ((size_t)b * 64 + d) * L;

    {
        const int l0 = tid * 4;
        float4 d4 = *(const float4*)(mdelta + base + l0);
        float4 u4 = *(const float4*)(mu + base + l0);
        float bias = mdt_b[d];
        float dv[4] = {d4.x, d4.y, d4.z, d4.w};
        float uv[4] = {u4.x, u4.y, u4.z, u4.w};
        #pragma unroll
        for (int t = 0; t < 4; ++t) {
            float dt = softplusf(dv[t] + bias);
            dtdu[tid >> 2][(tid & 3) * 4 + t] = make_float2(dt, dt * uv[t]);
        }
    }
    __syncthreads();

    const int c = tid >> 2;            // chunk 0..63 (16 steps)
    const int n = tid & 3;             // state
    const float Adn = -__expf(mA_log[d * 4 + n]);

    float s = 0.f, sumdt = 0.f;
    {
        const float* bp = mxdbl + ((size_t)b * 12 + 4 + n) * L + c * 16;
        for (int q = 0; q < 4; ++q) {
            float4 b4 = *(const float4*)(bp + q * 4);
            float bv[4] = {b4.x, b4.y, b4.z, b4.w};
            #pragma unroll
            for (int t = 0; t < 4; ++t) {
                float2 dd = dtdu[c][q * 4 + t];
                float a = __expf(dd.x * Adn);
                s = fmaf(a, s, dd.y * bv[t]);
                sumdt += dd.x;
            }
        }
    }
    PS[n][c] = make_float2(__expf(sumdt * Adn), s);
    __syncthreads();

    float s0 = 0.f;
    for (int j = 0; j < c; ++j) {
        float2 ps = PS[n][j];
        s0 = fmaf(ps.x, s0, ps.y);
    }

    {
        const float* bp = mxdbl + ((size_t)b * 12 + 4 + n) * L + c * 16;
        const float* cp = mxdbl + ((size_t)b * 12 + 8 + n) * L + c * 16;
        const float* up = mu + base + c * 16;
        const float* zp = mxz + ((size_t)b * 128 + 64 + d) * L + c * 16;
        const float Dd = mDp[d];
        float s2 = s0;
        for (int q = 0; q < 4; ++q) {
            float4 b4 = *(const float4*)(bp + q * 4);
            float4 c4 = *(const float4*)(cp + q * 4);
            float4 u4 = *(const float4*)(up + q * 4);
            float4 z4 = *(const float4*)(zp + q * 4);
            float bv[4] = {b4.x, b4.y, b4.z, b4.w};
            float cv[4] = {c4.x, c4.y, c4.z, c4.w};
            float uv[4] = {u4.x, u4.y, u4.z, u4.w};
            float zv[4] = {z4.x, z4.y, z4.z, z4.w};
            float yv[4];
            #pragma unroll
            for (int t = 0; t < 4; ++t) {
                float2 dd = dtdu[c][q * 4 + t];
                float a = __expf(dd.x * Adn);
                s2 = fmaf(a, s2, dd.y * bv[t]);
                float p = sum4(s2 * cv[t]);
                yv[t] = (p + Dd * uv[t]) * siluf(zv[t]);
            }
            if (n == 0)
                *(float4*)(ym + base + c * 16 + q * 4) = make_float4(yv[0], yv[1], yv[2], yv[3]);
        }
    }
}

// ---------------------------------------------------------------------------
extern "C" void kernel_launch(void* const* d_in, const int* in_sizes, int n_in,
                              void* d_out, int out_size, void* d_ws, size_t ws_size,
                              hipStream_t stream)
{
    const float* h         = (const float*)d_in[0];
    const float* in_w      = (const float*)d_in[1];
    const float* conv_w    = (const float*)d_in[2];
    const float* conv_b    = (const float*)d_in[3];
    const float* xproj_w   = (const float*)d_in[4];
    const float* dt_out_w  = (const float*)d_in[5];
    const float* dt_out_b  = (const float*)d_in[6];
    const float* A_log     = (const float*)d_in[7];
    const float* Dp        = (const float*)d_in[8];
    const float* out_w     = (const float*)d_in[9];
    const float* m_in_w    = (const float*)d_in[10];
    const float* m_conv_w  = (const float*)d_in[11];
    const float* m_conv_b  = (const float*)d_in[12];
    const float* m_xproj_w = (const float*)d_in[13];
    const float* m_dt_w    = (const float*)d_in[14];
    const float* m_dt_b    = (const float*)d_in[15];
    const float* m_A_log   = (const float*)d_in[16];
    const float* m_Dp      = (const float*)d_in[17];
    const float* m_out_w   = (const float*)d_in[18];
    float* out = (float*)d_out;

    const int B = 2, L = 1024, dm = 1024, di = 2048;

    float* ws     = (float*)d_ws;
    float* xz     = ws;                              // B*4096*L (x-rows reused as y)
    float* xconv  = xz     + (size_t)B * 2 * di * L; // B*2048*L
    float* xdbl   = xconv  + (size_t)B * di * L;     // B*96*L
    float* mxz    = xdbl   + (size_t)B * 96 * L;     // B*128*L
    float* mxconv = mxz    + (size_t)B * 128 * L;    // B*64*L
    float* mxdbl  = mxconv + (size_t)B * 64 * L;     // B*12*L
    float* mdelta = mxdbl  + (size_t)B * 12 * L;     // B*64*L
    float* ym     = mdelta + (size_t)B * 64 * L;     // B*64*L
    float* dtm    = ym     + (size_t)B * 64 * L;     // B*64*L
    float* delta  = dtm    + (size_t)B * 64 * L;     // B*2048*L
    ushort* yt    = (ushort*)delta;                  // bf16 y^T (after scan)
    float* part   = delta;                           // split-K partials (early)

    dim3 blk(256);

    // 1. xz[b,e,l] = sum_d in_w[e,d]*h[b,l,d]   (bf16 MFMA NT, fp32 out)
    mfma_gemm_nt<128, true, true><<<dim3(4096 / 128, L / 128, B), blk, 0, stream>>>(
        in_w, h, xz, 2 * di, L, dm, 0LL, (long long)L * dm, (long long)2 * di * L);

    // 2. x = silu(causal_conv(xz[:, :di]))  (vectorized W=4)
    {
        int total = B * di * (L / 4);
        conv4_silu_kernel<<<dim3((total + 255) / 256), blk, 0, stream>>>(
            xz, conv_w, conv_b, xconv, B, di, L, 2 * di);
    }

    // 3. xdbl = xproj_w @ xconv  (split-K=16 + deterministic reduce)
    {
        const int KS = 16;
        gemm_nn_splitk<<<dim3(2, 16, B * KS), blk, 0, stream>>>(
            xproj_w, xconv, part, 96, L, di, KS, (long long)di * L);
        int slab = 96 * L;
        reduce_splitk<<<dim3((slab / 4 + 255) / 256, B), blk, 0, stream>>>(
            part, xdbl, slab, KS);
    }

    // 4. inner in_proj
    gemm_kernel<false, true, false, false><<<dim3(2, 16, B), blk, 0, stream>>>(
        m_in_w, xdbl, nullptr, mxz, 128, L, 64, (long long)96 * L, (long long)128 * L);

    // 5. inner conv+silu (width 2)
    {
        int total = B * 64 * L;
        conv_silu_kernel<<<dim3((total + 255) / 256), blk, 0, stream>>>(
            mxz, m_conv_w, m_conv_b, mxconv, B, 64, L, 2, 128);
    }

    // 6+7. fused inner x_proj + dt
    inner_xproj_dt_kernel<<<dim3(L / 64, B), blk, 0, stream>>>(
        mxconv, m_xproj_w, m_dt_w, mxdbl, mdelta, L);

    // 8. inner selective scan -> ym
    scan_inner3_kernel<<<dim3(64, B), blk, 0, stream>>>(
        mdelta, mxconv, mxz, mxdbl, m_A_log, m_Dp, m_dt_b, ym, L);

    // 9. inner out_proj
    gemm_kernel<false, true, false, false><<<dim3(1, 16, B), blk, 0, stream>>>(
        m_out_w, ym, nullptr, dtm, 64, L, 64, (long long)64 * L, (long long)64 * L);

    // 10. delta = clip(dt_out_w @ dtm + dt_out_b, +-6)   (overwrites partials)
    gemm_kernel<false, true, true, true><<<dim3(32, 16, B), blk, 0, stream>>>(
        dt_out_w, dtm, dt_out_b, delta, di, L, 64, (long long)64 * L, (long long)di * L);

    // 11. outer selective scan -> y into the dead x-rows of xz (fp32)
    scan_outer3_kernel<<<dim3(di, B), blk, 0, stream>>>(
        delta, xconv, xz, xdbl, A_log, Dp, dt_out_b, xz, di, L, (long long)2 * di * L);

    // 11b. y (b,di,L in xz rows) -> yt (b,L,di) bf16 (delta buffer dead again)
    transpose_f32_bf16<<<dim3(L / 32, di / 32, B), blk, 0, stream>>>(
        xz, yt, di, L, (long long)2 * di * L);

    // 12. out[(b,l),e] = sum_d yt[(b,l),d]*out_w[e,d]  (batch-merged M=2048)
    mfma_gemm_nt<64, false, true><<<dim3(B * L / 128, dm / 64, 1), blk, 0, stream>>>(
        yt, out_w, out, B * L, dm, di, 0LL, 0LL, 0LL);
}

// Round 7
// 295.700 us; speedup vs baseline: 7.6120x; 1.3263x over previous
//
#include <hip/hip_runtime.h>
#include <hip/hip_bf16.h>

#define DEVFN __device__ __forceinline__

DEVFN float siluf(float x)     { return x / (1.f + __expf(-x)); }
DEVFN float softplusf(float x) { return fmaxf(x, 0.f) + log1pf(__expf(-fabsf(x))); }

DEVFN ushort f2bf(float f) {               // RNE fp32 -> bf16
    union { float f; unsigned u; } v; v.f = f;
    unsigned r = (v.u + 0x7FFF + ((v.u >> 16) & 1)) >> 16;
    return (ushort)r;
}

// DPP cross-lane add: x + lane_perm(x). 0x128=row_ror:8, 0x124=row_ror:4,
// 0x4E=quad_perm xor2, 0xB1=quad_perm xor1.
template<int CTRL>
DEVFN float dpp_addf(float x) {
    union { float f; int i; } a, r;
    a.f = x;
    r.i = __builtin_amdgcn_update_dpp(0, a.i, CTRL, 0xF, 0xF, true);
    return x + r.f;
}
DEVFN float sum16(float p) {
    p = dpp_addf<0x128>(p);
    p = dpp_addf<0x124>(p);
    p = dpp_addf<0x4E>(p);
    p = dpp_addf<0xB1>(p);
    return p;
}
DEVFN float sum4(float p) {
    p = dpp_addf<0x4E>(p);
    p = dpp_addf<0xB1>(p);
    return p;
}

typedef __bf16 bf16x8 __attribute__((ext_vector_type(8)));
typedef float  f32x4  __attribute__((ext_vector_type(4)));
typedef ushort us8    __attribute__((ext_vector_type(8)));

// ---------------------------------------------------------------------------
// bf16 MFMA NT GEMM: C(M,N) += A(M,K) * B^T(N,K); A,B k-contiguous.
template<int BN, bool A_F32, bool B_F32>
__global__ __launch_bounds__(256) void mfma_gemm_nt(
    const void* __restrict__ Av, const void* __restrict__ Bv,
    float* __restrict__ C, int M, int N, int K,
    long long Abs, long long Bbs, long long Cbs)
{
    constexpr int BM = 128;
    constexpr int NFR = BN / 32;
    __shared__ __align__(16) ushort As[BM][40];
    __shared__ __align__(16) ushort Bs[BN][40];

    const int tid = threadIdx.x;
    const int m0 = blockIdx.x * BM;
    const int n0 = blockIdx.y * BN;
    const int b  = blockIdx.z;
    const int lane = tid & 63;
    const int wid  = tid >> 6;
    const int wr   = wid >> 1;
    const int wc   = wid & 1;
    const int fr   = lane & 15;
    const int kq   = lane >> 4;

    f32x4 acc[4][NFR];
    #pragma unroll
    for (int i = 0; i < 4; ++i)
        #pragma unroll
        for (int j = 0; j < NFR; ++j)
            acc[i][j] = (f32x4){0.f, 0.f, 0.f, 0.f};

    const int arow = tid >> 1;
    const int kh   = (tid & 1) * 16;

    for (int kt = 0; kt < K; kt += 32) {
        if (kt) __syncthreads();
        {
            const long long off = (long long)b * Abs + (long long)(m0 + arow) * K + kt + kh;
            us8 lo, hi;
            if (A_F32) {
                const float4* p = (const float4*)((const float*)Av + off);
                float4 v0 = p[0], v1 = p[1], v2 = p[2], v3 = p[3];
                lo = (us8){f2bf(v0.x), f2bf(v0.y), f2bf(v0.z), f2bf(v0.w),
                           f2bf(v1.x), f2bf(v1.y), f2bf(v1.z), f2bf(v1.w)};
                hi = (us8){f2bf(v2.x), f2bf(v2.y), f2bf(v2.z), f2bf(v2.w),
                           f2bf(v3.x), f2bf(v3.y), f2bf(v3.z), f2bf(v3.w)};
            } else {
                const us8* p = (const us8*)((const ushort*)Av + off);
                lo = p[0]; hi = p[1];
            }
            *(us8*)&As[arow][kh]     = lo;
            *(us8*)&As[arow][kh + 8] = hi;
        }
        if (BN == BM || arow < BN) {
            const long long off = (long long)b * Bbs + (long long)(n0 + arow) * K + kt + kh;
            us8 lo, hi;
            if (B_F32) {
                const float4* p = (const float4*)((const float*)Bv + off);
                float4 v0 = p[0], v1 = p[1], v2 = p[2], v3 = p[3];
                lo = (us8){f2bf(v0.x), f2bf(v0.y), f2bf(v0.z), f2bf(v0.w),
                           f2bf(v1.x), f2bf(v1.y), f2bf(v1.z), f2bf(v1.w)};
                hi = (us8){f2bf(v2.x), f2bf(v2.y), f2bf(v2.z), f2bf(v2.w),
                           f2bf(v3.x), f2bf(v3.y), f2bf(v3.z), f2bf(v3.w)};
            } else {
                const us8* p = (const us8*)((const ushort*)Bv + off);
                lo = p[0]; hi = p[1];
            }
            *(us8*)&Bs[arow][kh]     = lo;
            *(us8*)&Bs[arow][kh + 8] = hi;
        }
        __syncthreads();

        bf16x8 af[4], bfv[NFR];
        #pragma unroll
        for (int mi = 0; mi < 4; ++mi)
            af[mi] = *(const bf16x8*)&As[wr * 64 + mi * 16 + fr][kq * 8];
        #pragma unroll
        for (int ni = 0; ni < NFR; ++ni)
            bfv[ni] = *(const bf16x8*)&Bs[wc * (BN / 2) + ni * 16 + fr][kq * 8];
        #pragma unroll
        for (int mi = 0; mi < 4; ++mi)
            #pragma unroll
            for (int ni = 0; ni < NFR; ++ni)
                acc[mi][ni] = __builtin_amdgcn_mfma_f32_16x16x32_bf16(
                    af[mi], bfv[ni], acc[mi][ni], 0, 0, 0);
    }

    #pragma unroll
    for (int mi = 0; mi < 4; ++mi) {
        const int gm = m0 + wr * 64 + mi * 16 + kq * 4;
        #pragma unroll
        for (int ni = 0; ni < NFR; ++ni) {
            const int gn = n0 + wc * (BN / 2) + ni * 16 + fr;
            f32x4 v = acc[mi][ni];
            #pragma unroll
            for (int r = 0; r < 4; ++r)
                C[(long long)b * Cbs + (long long)(gm + r) * N + gn] = v[r];
        }
    }
}

// ---------------------------------------------------------------------------
// y (b, D, L) fp32 (batch stride Ybs) -> yt (b, L, D) bf16 (contiguous).
__global__ __launch_bounds__(256) void transpose_f32_bf16(
    const float* __restrict__ y, ushort* __restrict__ yt,
    int D, int Lx, long long Ybs)
{
    __shared__ float ts[32][33];
    const int l0 = blockIdx.x * 32, d0 = blockIdx.y * 32, b = blockIdx.z;
    const int tx = threadIdx.x & 31, ty = threadIdx.x >> 5;
    const float* yb = y + (size_t)b * Ybs + (size_t)d0 * Lx + l0;
    #pragma unroll
    for (int r = ty; r < 32; r += 8)
        ts[r][tx] = yb[(size_t)r * Lx + tx];
    __syncthreads();
    ushort* ytb = yt + ((size_t)b * Lx + l0) * D + d0;
    #pragma unroll
    for (int r = ty; r < 32; r += 8)
        ytb[(size_t)r * D + tx] = f2bf(ts[tx][r]);
}

// ---------------------------------------------------------------------------
// Generic tiled fp32 GEMM (small ops). Xld = row stride of X's leading dim
// (BKC: X is (N,K)-shaped rows of stride Xld; !BKC: X is (K,N) rows stride Xld).
template<bool BKC, bool OUTM, bool CLIP, bool BIAS>
__global__ __launch_bounds__(256) void gemm_kernel(
    const float* __restrict__ A, const float* __restrict__ X,
    const float* __restrict__ bias, float* __restrict__ C,
    int M, int N, int K, int Xld, long long Xbs, long long Cbs)
{
    __shared__ __align__(16) float As[16][68];
    __shared__ __align__(16) float Xs[16][68];
    const int m0 = blockIdx.x * 64;
    const int n0 = blockIdx.y * 64;
    const int b  = blockIdx.z;
    const float* Xb = X + (long long)b * Xbs;
    const int tid = threadIdx.x;
    const int te = tid & 15, tl = tid >> 4;
    float acc[4][4] = {};

    for (int k0 = 0; k0 < K; k0 += 16) {
        #pragma unroll
        for (int idx = tid; idx < 1024; idx += 256) {
            int e = idx >> 4, kk = idx & 15;
            int m = m0 + e, k = k0 + kk;
            As[kk][e] = (m < M && k < K) ? A[(long long)m * K + k] : 0.f;
        }
        if (BKC) {
            #pragma unroll
            for (int idx = tid; idx < 1024; idx += 256) {
                int n = idx >> 4, kk = idx & 15;
                int nn = n0 + n, k = k0 + kk;
                Xs[kk][n] = (nn < N && k < K) ? Xb[(long long)nn * Xld + k] : 0.f;
            }
        } else {
            #pragma unroll
            for (int idx = tid; idx < 1024; idx += 256) {
                int kk = idx >> 6, n = idx & 63;
                int nn = n0 + n, k = k0 + kk;
                Xs[kk][n] = (nn < N && k < K) ? Xb[(long long)k * Xld + nn] : 0.f;
            }
        }
        __syncthreads();
        #pragma unroll
        for (int kk = 0; kk < 16; ++kk) {
            float4 a4 = *reinterpret_cast<const float4*>(&As[kk][te * 4]);
            float4 x4 = *reinterpret_cast<const float4*>(&Xs[kk][tl * 4]);
            float av[4] = {a4.x, a4.y, a4.z, a4.w};
            float xv[4] = {x4.x, x4.y, x4.z, x4.w};
            #pragma unroll
            for (int i = 0; i < 4; ++i)
                #pragma unroll
                for (int j = 0; j < 4; ++j)
                    acc[i][j] += av[i] * xv[j];
        }
        __syncthreads();
    }

    #pragma unroll
    for (int i = 0; i < 4; ++i) {
        int m = m0 + te * 4 + i;
        if (m >= M) continue;
        float bv = BIAS ? bias[m] : 0.f;
        #pragma unroll
        for (int j = 0; j < 4; ++j) {
            int n = n0 + tl * 4 + j;
            if (n >= N) continue;
            float v = acc[i][j] + bv;
            if (CLIP) v = fminf(fmaxf(v, -6.f), 6.f);
            if (OUTM) C[(long long)b * Cbs + (long long)m * N + n] = v;
            else      C[(long long)b * Cbs + (long long)n * M + m] = v;
        }
    }
}

// ---------------------------------------------------------------------------
// Split-K xproj with transposed output: P[(b,ks)][l][e] = partial
// sum_d xproj_w[e][d] * xconv[b][d][l], e<96. Grid (L/64, KS, B).
__global__ __launch_bounds__(256) void xprojT_splitk(
    const float* __restrict__ W, const float* __restrict__ X,
    float* __restrict__ P, int L, int K, int KS)
{
    __shared__ float Xs[16][68];
    __shared__ float Ws[16][100];
    const int l0 = blockIdx.x * 64;
    const int ks = blockIdx.y;
    const int b  = blockIdx.z;
    const int Kc = K / KS;
    const int tid = threadIdx.x;
    const int tl = (tid & 15) * 4;
    const int te = (tid >> 4) * 6;
    float acc[4][6] = {};
    const float* Xb = X + (size_t)b * K * L;

    for (int d0 = ks * Kc; d0 < (ks + 1) * Kc; d0 += 16) {
        #pragma unroll
        for (int o = tid; o < 1024; o += 256) {
            int dd = o >> 6, l = o & 63;
            Xs[dd][l] = Xb[(size_t)(d0 + dd) * L + l0 + l];
        }
        #pragma unroll
        for (int o = tid; o < 1536; o += 256) {
            int e = o >> 4, dd = o & 15;
            Ws[dd][e] = W[(size_t)e * K + d0 + dd];
        }
        __syncthreads();
        #pragma unroll
        for (int dd = 0; dd < 16; ++dd) {
            float4 x4 = *(const float4*)&Xs[dd][tl];
            float xv[4] = {x4.x, x4.y, x4.z, x4.w};
            float wv[6];
            #pragma unroll
            for (int j = 0; j < 6; ++j) wv[j] = Ws[dd][te + j];
            #pragma unroll
            for (int i = 0; i < 4; ++i)
                #pragma unroll
                for (int j = 0; j < 6; ++j)
                    acc[i][j] += xv[i] * wv[j];
        }
        __syncthreads();
    }

    float* Pz = P + ((size_t)(b * KS + ks) * L + l0) * 96;
    #pragma unroll
    for (int i = 0; i < 4; ++i)
        #pragma unroll
        for (int j = 0; j < 6; ++j)
            Pz[(size_t)(tl + i) * 96 + te + j] = acc[i][j];
}

__global__ __launch_bounds__(256) void reduce_splitk(
    const float* __restrict__ P, float* __restrict__ C, int slab, int KS)
{
    const int i4 = blockIdx.x * 256 + threadIdx.x;
    const int b  = blockIdx.y;
    if (i4 * 4 >= slab) return;
    const float* base = P + (size_t)b * KS * slab + (size_t)i4 * 4;
    float4 acc = make_float4(0.f, 0.f, 0.f, 0.f);
    for (int ks = 0; ks < KS; ++ks) {
        float4 v = *(const float4*)(base + (size_t)ks * slab);
        acc.x += v.x; acc.y += v.y; acc.z += v.z; acc.w += v.w;
    }
    *(float4*)(C + (size_t)b * slab + (size_t)i4 * 4) = acc;
}

// ---------------------------------------------------------------------------
// Vectorized causal depthwise conv W=4 + SiLU, 4 outputs/thread.
__global__ __launch_bounds__(256) void conv4_silu_kernel(
    const float* __restrict__ in, const float* __restrict__ w,
    const float* __restrict__ bias, float* __restrict__ out,
    int B, int D, int L, int IC)
{
    int idx = blockIdx.x * 256 + threadIdx.x;
    int nL4 = L >> 2;
    if (idx >= B * D * nL4) return;
    int l4 = (idx % nL4) * 4;
    int d  = (idx / nL4) % D;
    int b  = idx / (nL4 * D);
    const float* xp = in + ((size_t)b * IC + d) * L;
    float4 cur = *(const float4*)(xp + l4);
    float4 prev = make_float4(0.f, 0.f, 0.f, 0.f);
    if (l4) prev = *(const float4*)(xp + l4 - 4);
    const float4 wv = *(const float4*)(w + d * 4);
    float bv = bias[d];
    float y0 = bv + wv.x*prev.y + wv.y*prev.z + wv.z*prev.w + wv.w*cur.x;
    float y1 = bv + wv.x*prev.z + wv.y*prev.w + wv.z*cur.x  + wv.w*cur.y;
    float y2 = bv + wv.x*prev.w + wv.y*cur.x  + wv.z*cur.y  + wv.w*cur.z;
    float y3 = bv + wv.x*cur.x  + wv.y*cur.y  + wv.z*cur.z  + wv.w*cur.w;
    *(float4*)(out + ((size_t)b * D + d) * L + l4) =
        make_float4(siluf(y0), siluf(y1), siluf(y2), siluf(y3));
}

// Scalar causal conv (inner, W=2) + SiLU.
__global__ __launch_bounds__(256) void conv_silu_kernel(
    const float* __restrict__ in, const float* __restrict__ w,
    const float* __restrict__ bias, float* __restrict__ out,
    int B, int D, int L, int W, int IC)
{
    int idx = blockIdx.x * 256 + threadIdx.x;
    int total = B * D * L;
    if (idx >= total) return;
    int l = idx % L;
    int d = (idx / L) % D;
    int b = idx / (L * D);
    const float* xp = in + (size_t)b * IC * L + (size_t)d * L;
    float acc = bias[d];
    for (int i = 0; i < W; ++i) {
        int li = l - (W - 1) + i;
        if (li >= 0) acc += w[d * W + i] * xp[li];
    }
    out[(size_t)b * D * L + (size_t)d * L + l] = siluf(acc);
}

// ---------------------------------------------------------------------------
// Fused inner x_proj + dt matmuls. mxdblT (b, L, 12) l-major; mdelta (b,64,L).
// Grid (L/64, B), 256 threads.
__global__ __launch_bounds__(256) void inner_xproj_dt_kernel(
    const float* __restrict__ mxconv, const float* __restrict__ xw,
    const float* __restrict__ dtw, float* __restrict__ mxdblT,
    float* __restrict__ mdelta, int L)
{
    __shared__ float xs[64][65];
    __shared__ float xwl[12][64];
    __shared__ float dtl[64][4];
    __shared__ float xd[4][65];
    const int tid = threadIdx.x;
    const int l0 = blockIdx.x * 64;
    const int b  = blockIdx.y;

    for (int o = tid; o < 4096; o += 256) {
        int k = o >> 6, l = o & 63;
        xs[k][l] = mxconv[((size_t)b * 64 + k) * L + l0 + l];
    }
    if (tid < 768) xwl[tid >> 6][tid & 63] = xw[tid];
    dtl[tid >> 2][tid & 3] = dtw[tid];
    __syncthreads();

    for (int o = tid; o < 768; o += 256) {
        int e = o >> 6, l = o & 63;
        float acc = 0.f;
        #pragma unroll
        for (int k = 0; k < 64; ++k) acc += xwl[e][k] * xs[k][l];
        mxdblT[((size_t)b * L + l0 + l) * 12 + e] = acc;
        if (e < 4) xd[e][l] = acc;
    }
    __syncthreads();

    for (int o = tid; o < 4096; o += 256) {
        int dch = o >> 6, l = o & 63;
        float acc = dtl[dch][0] * xd[0][l] + dtl[dch][1] * xd[1][l]
                  + dtl[dch][2] * xd[2][l] + dtl[dch][3] * xd[3][l];
        mdelta[((size_t)b * 64 + dch) * L + l0 + l] = acc;
    }
}

// ---------------------------------------------------------------------------
// Outer selective scan v4: 1 channel/block, 16 chunks x 16 states.
// B/C from xdblT (b, L, 96) -> coalesced 16-lane reads. Grid (Dch, B).
__global__ __launch_bounds__(256) void scan_outer4_kernel(
    const float* __restrict__ delta, const float* __restrict__ u,
    const float* __restrict__ xz, const float* __restrict__ xdblT,
    const float* __restrict__ A_log, const float* __restrict__ Dp,
    const float* __restrict__ dt_bias, float* __restrict__ y,
    int Dch, int L, long long Ybs)
{
    __shared__ float2 dtdu[16][66];
    __shared__ float2 PS[16][17];

    const int tid = threadIdx.x;
    const int b = blockIdx.y;
    const int d = blockIdx.x;
    const size_t rbase = ((size_t)b * Dch + d) * L;

    {
        const int l0 = tid * 4;
        float4 d4 = *(const float4*)(delta + rbase + l0);
        float4 u4 = *(const float4*)(u + rbase + l0);
        float bias = dt_bias[d];
        float dv[4] = {d4.x, d4.y, d4.z, d4.w};
        float uv[4] = {u4.x, u4.y, u4.z, u4.w};
        #pragma unroll
        for (int t = 0; t < 4; ++t) {
            float dt = softplusf(dv[t] + bias);
            dtdu[tid >> 4][(tid & 15) * 4 + t] = make_float2(dt, dt * uv[t]);
        }
    }
    __syncthreads();

    const int c = tid >> 4;
    const int n = tid & 15;
    const float Adn = -__expf(A_log[d * 16 + n]);
    const float* brow = xdblT + ((size_t)b * L + (size_t)c * 64) * 96 + 64 + n;

    // phase 1: chunk-local scan
    float s = 0.f, sumdt = 0.f;
    for (int q = 0; q < 16; ++q) {
        #pragma unroll
        for (int t = 0; t < 4; ++t) {
            int l = q * 4 + t;
            float bv = brow[(size_t)l * 96];
            float2 dd = dtdu[c][l];
            float a = __expf(dd.x * Adn);
            s = fmaf(a, s, dd.y * bv);
            sumdt += dd.x;
        }
    }
    PS[n][c] = make_float2(__expf(sumdt * Adn), s);
    __syncthreads();

    float s0 = 0.f;
    for (int j = 0; j < c; ++j) {
        float2 ps = PS[n][j];
        s0 = fmaf(ps.x, s0, ps.y);
    }

    // phase 2: rescan with init, DPP-reduce over states, emit y
    {
        const size_t ybase = (size_t)b * Ybs + (size_t)d * L + (size_t)c * 64;
        const float* up = u + rbase + (size_t)c * 64;
        const float* zp = xz + ((size_t)b * 2 * Dch + Dch + d) * L + c * 64;
        const float Dd = Dp[d];
        float s2 = s0;
        for (int q = 0; q < 16; ++q) {
            float4 u4 = *(const float4*)(up + q * 4);
            float4 z4 = *(const float4*)(zp + q * 4);
            float uv[4] = {u4.x, u4.y, u4.z, u4.w};
            float zv[4] = {z4.x, z4.y, z4.z, z4.w};
            float yv[4];
            #pragma unroll
            for (int t = 0; t < 4; ++t) {
                int l = q * 4 + t;
                float bv = brow[(size_t)l * 96];
                float cv = brow[(size_t)l * 96 + 16];
                float2 dd = dtdu[c][l];
                float a = __expf(dd.x * Adn);
                s2 = fmaf(a, s2, dd.y * bv);
                float p = sum16(s2 * cv);
                yv[t] = (p + Dd * uv[t]) * siluf(zv[t]);
            }
            if (n == 0)
                *(float4*)(y + ybase + q * 4) = make_float4(yv[0], yv[1], yv[2], yv[3]);
        }
    }
}

// ---------------------------------------------------------------------------
// Inner selective scan v4: 64 chunks x 4 states; B/C from mxdblT (b, L, 12).
__global__ __launch_bounds__(256) void scan_inner4_kernel(
    const float* __restrict__ mdelta, const float* __restrict__ mu,
    const float* __restrict__ mxz, const float* __restrict__ mxdblT,
    const float* __restrict__ mA_log, const float* __restrict__ mDp,
    const float* __restrict__ mdt_b, float* __restrict__ ym, int L)
{
    __shared__ float2 dtdu[64][17];
    __shared__ float2 PS[4][66];

    const int tid = threadIdx.x;
    const int b = blockIdx.y;
    const int d = blockIdx.x;
    const size_t base = ((size_t)b * 64 + d) * L;

    {
        const int l0 = tid * 4;
        float4 d4 = *(const float4*)(mdelta + base + l0);
        float4 u4 = *(const float4*)(mu + base + l0);
        float bias = mdt_b[d];
        float dv[4] = {d4.x, d4.y, d4.z, d4.w};
        float uv[4] = {u4.x, u4.y, u4.z, u4.w};
        #pragma unroll
        for (int t = 0; t < 4; ++t) {
            float dt = softplusf(dv[t] + bias);
            dtdu[tid >> 2][(tid & 3) * 4 + t] = make_float2(dt, dt * uv[t]);
        }
    }
    __syncthreads();

    const int c = tid >> 2;
    const int n = tid & 3;
    const float Adn = -__expf(mA_log[d * 4 + n]);
    const float* brow = mxdblT + ((size_t)b * L + (size_t)c * 16) * 12 + 4 + n;

    float s = 0.f, sumdt = 0.f;
    for (int l = 0; l < 16; ++l) {
        float bv = brow[(size_t)l * 12];
        float2 dd = dtdu[c][l];
        float a = __expf(dd.x * Adn);
        s = fmaf(a, s, dd.y * bv);
        sumdt += dd.x;
    }
    PS[n][c] = make_float2(__expf(sumdt * Adn), s);
    __syncthreads();

    float s0 = 0.f;
    for (int j = 0; j < c; ++j) {
        float2 ps = PS[n][j];
        s0 = fmaf(ps.x, s0, ps.y);
    }

    {
        const float* up = mu + base + c * 16;
        const float* zp = mxz + ((size_t)b * 128 + 64 + d) * L + c * 16;
        const float Dd = mDp[d];
        float s2 = s0;
        for (int q = 0; q < 4; ++q) {
            float4 u4 = *(const float4*)(up + q * 4);
            float4 z4 = *(const float4*)(zp + q * 4);
            float uv[4] = {u4.x, u4.y, u4.z, u4.w};
            float zv[4] = {z4.x, z4.y, z4.z, z4.w};
            float yv[4];
            #pragma unroll
            for (int t = 0; t < 4; ++t) {
                int l = q * 4 + t;
                float bv = brow[(size_t)l * 12];
                float cv = brow[(size_t)l * 12 + 4];
                float2 dd = dtdu[c][l];
                float a = __expf(dd.x * Adn);
                s2 = fmaf(a, s2, dd.y * bv);
                float p = sum4(s2 * cv);
                yv[t] = (p + Dd * uv[t]) * siluf(zv[t]);
            }
            if (n == 0)
                *(float4*)(ym + base + c * 16 + q * 4) = make_float4(yv[0], yv[1], yv[2], yv[3]);
        }
    }
}

// ---------------------------------------------------------------------------
extern "C" void kernel_launch(void* const* d_in, const int* in_sizes, int n_in,
                              void* d_out, int out_size, void* d_ws, size_t ws_size,
                              hipStream_t stream)
{
    const float* h         = (const float*)d_in[0];
    const float* in_w      = (const float*)d_in[1];
    const float* conv_w    = (const float*)d_in[2];
    const float* conv_b    = (const float*)d_in[3];
    const float* xproj_w   = (const float*)d_in[4];
    const float* dt_out_w  = (const float*)d_in[5];
    const float* dt_out_b  = (const float*)d_in[6];
    const float* A_log     = (const float*)d_in[7];
    const float* Dp        = (const float*)d_in[8];
    const float* out_w     = (const float*)d_in[9];
    const float* m_in_w    = (const float*)d_in[10];
    const float* m_conv_w  = (const float*)d_in[11];
    const float* m_conv_b  = (const float*)d_in[12];
    const float* m_xproj_w = (const float*)d_in[13];
    const float* m_dt_w    = (const float*)d_in[14];
    const float* m_dt_b    = (const float*)d_in[15];
    const float* m_A_log   = (const float*)d_in[16];
    const float* m_Dp      = (const float*)d_in[17];
    const float* m_out_w   = (const float*)d_in[18];
    float* out = (float*)d_out;

    const int B = 2, L = 1024, dm = 1024, di = 2048;

    float* ws     = (float*)d_ws;
    float* xz     = ws;                              // B*4096*L (x-rows reused as y)
    float* xconv  = xz     + (size_t)B * 2 * di * L; // B*2048*L
    float* xdblT  = xconv  + (size_t)B * di * L;     // B*L*96 (l-major)
    float* mxz    = xdblT  + (size_t)B * 96 * L;     // B*128*L
    float* mxconv = mxz    + (size_t)B * 128 * L;    // B*64*L
    float* mxdblT = mxconv + (size_t)B * 64 * L;     // B*L*12 (l-major)
    float* mdelta = mxdblT + (size_t)B * 12 * L;     // B*64*L
    float* ym     = mdelta + (size_t)B * 64 * L;     // B*64*L
    float* dtm    = ym     + (size_t)B * 64 * L;     // B*64*L
    float* delta  = dtm    + (size_t)B * 64 * L;     // B*2048*L
    ushort* yt    = (ushort*)delta;                  // bf16 y^T (after scan)
    float* part   = delta;                           // split-K partials (early)

    dim3 blk(256);

    // 1. xz[b,e,l] = sum_d in_w[e,d]*h[b,l,d]   (bf16 MFMA NT, fp32 out)
    mfma_gemm_nt<128, true, true><<<dim3(4096 / 128, L / 128, B), blk, 0, stream>>>(
        in_w, h, xz, 2 * di, L, dm, 0LL, (long long)L * dm, (long long)2 * di * L);

    // 2. x = silu(causal_conv(xz[:, :di]))  (vectorized W=4)
    {
        int total = B * di * (L / 4);
        conv4_silu_kernel<<<dim3((total + 255) / 256), blk, 0, stream>>>(
            xz, conv_w, conv_b, xconv, B, di, L, 2 * di);
    }

    // 3. xdblT[b,l,e] = sum_d xproj_w[e,d]*xconv[b,d,l]  (split-K + reduce)
    {
        const int KS = 16;
        xprojT_splitk<<<dim3(L / 64, KS, B), blk, 0, stream>>>(
            xproj_w, xconv, part, L, di, KS);
        int slab = 96 * L;
        reduce_splitk<<<dim3((slab / 4 + 255) / 256, B), blk, 0, stream>>>(
            part, xdblT, slab, KS);
    }

    // 4. inner in_proj: mxz[b,e,l] = sum_k m_in_w[e,k]*xdblT[b,l,k] (k<64)
    gemm_kernel<true, true, false, false><<<dim3(2, 16, B), blk, 0, stream>>>(
        m_in_w, xdblT, nullptr, mxz, 128, L, 64, 96, (long long)96 * L, (long long)128 * L);

    // 5. inner conv+silu (width 2)
    {
        int total = B * 64 * L;
        conv_silu_kernel<<<dim3((total + 255) / 256), blk, 0, stream>>>(
            mxz, m_conv_w, m_conv_b, mxconv, B, 64, L, 2, 128);
    }

    // 6+7. fused inner x_proj + dt  (mxdblT in (b,l,12))
    inner_xproj_dt_kernel<<<dim3(L / 64, B), blk, 0, stream>>>(
        mxconv, m_xproj_w, m_dt_w, mxdblT, mdelta, L);

    // 8. inner selective scan -> ym
    scan_inner4_kernel<<<dim3(64, B), blk, 0, stream>>>(
        mdelta, mxconv, mxz, mxdblT, m_A_log, m_Dp, m_dt_b, ym, L);

    // 9. inner out_proj
    gemm_kernel<false, true, false, false><<<dim3(1, 16, B), blk, 0, stream>>>(
        m_out_w, ym, nullptr, dtm, 64, L, 64, L, (long long)64 * L, (long long)64 * L);

    // 10. delta = clip(dt_out_w @ dtm + dt_out_b, +-6)   (overwrites partials)
    gemm_kernel<false, true, true, true><<<dim3(32, 16, B), blk, 0, stream>>>(
        dt_out_w, dtm, dt_out_b, delta, di, L, 64, L, (long long)64 * L, (long long)di * L);

    // 11. outer selective scan -> y into the dead x-rows of xz (fp32)
    scan_outer4_kernel<<<dim3(di, B), blk, 0, stream>>>(
        delta, xconv, xz, xdblT, A_log, Dp, dt_out_b, xz, di, L, (long long)2 * di * L);

    // 11b. y (b,di,L in xz rows) -> yt (b,L,di) bf16 (delta buffer dead again)
    transpose_f32_bf16<<<dim3(L / 32, di / 32, B), blk, 0, stream>>>(
        xz, yt, di, L, (long long)2 * di * L);

    // 12. out[(b,l),e] = sum_d yt[(b,l),d]*out_w[e,d]  (batch-merged M=2048)
    mfma_gemm_nt<64, false, true><<<dim3(B * L / 128, dm / 64, 1), blk, 0, stream>>>(
        yt, out_w, out, B * L, dm, di, 0LL, 0LL, 0LL);
}